// Round 2
// baseline (1829.687 us; speedup 1.0000x reference)
//
#include <hip/hip_runtime.h>
#include <hip/hip_bf16.h>

// Problem constants (BlockInvariantPointAttention):
// B=2 N=2048 BQ=32 BK=128 NB=64 CS=384 CZ=128 CH=16 H=12 PQK=4 PV=8
// feats per row: o(192) | o_pt_f(288) | o_pt_d(96) | o_pair(384) = 960
// All float inputs/outputs are FLOAT32 on device; key_idx is int32.
// ws intermediates: pos* and feats f32; bbias/pairz bf16 (ours on both sides).

__device__ __forceinline__ float b2f(const __hip_bfloat16 x) { return __bfloat162float(x); }
__device__ __forceinline__ __hip_bfloat16 f2b(float x) { return __float2bfloat16(x); }

// ---------------------------------------------------------------------------
// K1: per-position LN(s) + projections (Wq|Wk|Wv|Wqp|Wkvp = 1152 cols) +
//     rigid rotations + point norms.  8 positions per block.
// ---------------------------------------------------------------------------
__global__ __launch_bounds__(256) void k_proj(
    const float* __restrict__ s, const float* __restrict__ trans,
    const float* __restrict__ rots,
    const float* __restrict__ g_s, const float* __restrict__ b_s,
    const float* __restrict__ Wq, const float* __restrict__ Wk,
    const float* __restrict__ Wv, const float* __restrict__ Wqp,
    const float* __restrict__ Wkvp,
    float* __restrict__ posq, float* __restrict__ posk, float* __restrict__ posv,
    float* __restrict__ posqp, float* __restrict__ poskp, float* __restrict__ posvp,
    float* __restrict__ posqn, float* __restrict__ poskn)
{
  __shared__ __align__(16) float srow[8][384];
  __shared__ __align__(16) float proj[8][1152];
  __shared__ float rt[8][12];
  const int tid = threadIdx.x;
  const int p0 = blockIdx.x * 8;

  // 8 rows x 384 = 768 float4
  for (int e = tid; e < 768; e += 256)
    ((float4*)&srow[0][0])[e] = ((const float4*)(s + (size_t)p0 * 384))[e];
  for (int e = tid; e < 8 * 12; e += 256) {
    int i = e / 12, c = e % 12;
    rt[i][c] = (c < 9) ? rots[(size_t)(p0 + i) * 9 + c]
                       : trans[(size_t)(p0 + i) * 3 + (c - 9)];
  }
  __syncthreads();

  // LayerNorm: wave w handles rows 2w, 2w+1
  {
    int w = tid >> 6, l = tid & 63;
    for (int ii = 0; ii < 2; ii++) {
      int i = w * 2 + ii;
      float s1 = 0.f, s2 = 0.f, x[6];
      #pragma unroll
      for (int j = 0; j < 6; j++) { x[j] = srow[i][l + j * 64]; s1 += x[j]; s2 += x[j] * x[j]; }
      #pragma unroll
      for (int m = 1; m < 64; m <<= 1) { s1 += __shfl_xor(s1, m, 64); s2 += __shfl_xor(s2, m, 64); }
      float mean = s1 * (1.f / 384.f);
      float var = s2 * (1.f / 384.f) - mean * mean;
      float rstd = rsqrtf(var + 1e-5f);
      #pragma unroll
      for (int j = 0; j < 6; j++) {
        int c = l + j * 64;
        srow[i][c] = (x[j] - mean) * rstd * g_s[c] + b_s[c];
      }
    }
  }
  __syncthreads();

  // Projections: each thread owns cols {tid, tid+256, ...}
  const float* wptr[5]; int wst[5]; int colv[5];
  #pragma unroll
  for (int j = 0; j < 5; j++) {
    int col = tid + j * 256;
    colv[j] = col;
    if (col < 192)       { wptr[j] = Wq   + col;         wst[j] = 192; }
    else if (col < 384)  { wptr[j] = Wk   + (col - 192); wst[j] = 192; }
    else if (col < 576)  { wptr[j] = Wv   + (col - 384); wst[j] = 192; }
    else if (col < 720)  { wptr[j] = Wqp  + (col - 576); wst[j] = 144; }
    else if (col < 1152) { wptr[j] = Wkvp + (col - 720); wst[j] = 432; }
    else                 { wptr[j] = Wq;                 wst[j] = 0;   }
  }
  float acc[5][8];
  #pragma unroll
  for (int j = 0; j < 5; j++)
    #pragma unroll
    for (int i = 0; i < 8; i++) acc[j][i] = 0.f;

  for (int r4 = 0; r4 < 384; r4 += 4) {
    float4 s4[8];
    #pragma unroll
    for (int i = 0; i < 8; i++) s4[i] = *(const float4*)&srow[i][r4];
    #pragma unroll
    for (int rr = 0; rr < 4; rr++) {
      int r = r4 + rr;
      #pragma unroll
      for (int j = 0; j < 5; j++) {
        if (colv[j] >= 1152) continue;
        float wv = wptr[j][(size_t)r * wst[j]];
        #pragma unroll
        for (int i = 0; i < 8; i++) acc[j][i] += ((const float*)&s4[i])[rr] * wv;
      }
    }
  }
  #pragma unroll
  for (int j = 0; j < 5; j++) {
    if (colv[j] < 1152)
      #pragma unroll
      for (int i = 0; i < 8; i++) proj[i][colv[j]] = acc[j][i];
  }
  __syncthreads();

  // Rotations: 8 rows x 192 points (48 q-pts + 144 kv-pts)
  for (int e = tid; e < 8 * 192; e += 256) {
    int i = e / 192, p = e % 192;
    float R0 = rt[i][0], R1 = rt[i][1], R2 = rt[i][2];
    float R3 = rt[i][3], R4 = rt[i][4], R5 = rt[i][5];
    float R6 = rt[i][6], R7 = rt[i][7], R8 = rt[i][8];
    float tx = rt[i][9], ty = rt[i][10], tz = rt[i][11];
    size_t pos = p0 + i;
    if (p < 48) {
      int base = 576 + p * 3;
      float v0 = proj[i][base], v1 = proj[i][base + 1], v2 = proj[i][base + 2];
      float o0 = R0 * v0 + R1 * v1 + R2 * v2 + tx;
      float o1 = R3 * v0 + R4 * v1 + R5 * v2 + ty;
      float o2 = R6 * v0 + R7 * v1 + R8 * v2 + tz;
      proj[i][base] = o0; proj[i][base + 1] = o1; proj[i][base + 2] = o2;
      posqp[pos * 144 + p * 3 + 0] = o0;
      posqp[pos * 144 + p * 3 + 1] = o1;
      posqp[pos * 144 + p * 3 + 2] = o2;
    } else {
      int p2 = p - 48;
      int base = 720 + p2 * 3;
      float v0 = proj[i][base], v1 = proj[i][base + 1], v2 = proj[i][base + 2];
      float o0 = R0 * v0 + R1 * v1 + R2 * v2 + tx;
      float o1 = R3 * v0 + R4 * v1 + R5 * v2 + ty;
      float o2 = R6 * v0 + R7 * v1 + R8 * v2 + tz;
      int h = p2 / 12, idx = p2 % 12;
      if (idx < 4) {
        proj[i][base] = o0; proj[i][base + 1] = o1; proj[i][base + 2] = o2;
        poskp[pos * 144 + h * 12 + idx * 3 + 0] = o0;
        poskp[pos * 144 + h * 12 + idx * 3 + 1] = o1;
        poskp[pos * 144 + h * 12 + idx * 3 + 2] = o2;
      } else {
        posvp[pos * 288 + h * 24 + (idx - 4) * 3 + 0] = o0;
        posvp[pos * 288 + h * 24 + (idx - 4) * 3 + 1] = o1;
        posvp[pos * 288 + h * 24 + (idx - 4) * 3 + 2] = o2;
      }
    }
  }
  __syncthreads();

  // Point norms per (row, head)
  for (int e = tid; e < 96; e += 256) {
    int i = e / 12, h = e % 12;
    size_t pos = p0 + i;
    float qs = 0.f, ks = 0.f;
    #pragma unroll
    for (int u = 0; u < 12; u++) {
      float a_ = proj[i][576 + h * 12 + u];
      qs += a_ * a_;
      float c_ = proj[i][720 + h * 36 + u];
      ks += c_ * c_;
    }
    posqn[pos * 12 + h] = qs;
    poskn[pos * 12 + h] = ks;
  }
  // q/k/v write-out
  for (int e = tid; e < 8 * 576; e += 256) {
    int i = e / 576, c = e % 576;
    size_t pos = p0 + i;
    float v = proj[i][c];
    if (c < 192)      posq[pos * 192 + c]         = v;
    else if (c < 384) posk[pos * 192 + (c - 192)] = v;
    else              posv[pos * 192 + (c - 384)] = v;
  }
}

// ---------------------------------------------------------------------------
// K2: z path. LN over CZ=128 then 44-col GEMV -> bbias(12) + pair_z(32), bf16.
// 512 pairs per block; register tile 8 pairs x 11 cols per thread.
// ---------------------------------------------------------------------------
__global__ __launch_bounds__(256) void k_z(
    const float* __restrict__ z,
    const float* __restrict__ g_z, const float* __restrict__ b_z,
    const float* __restrict__ Wb, const float* __restrict__ Wdz,
    __hip_bfloat16* __restrict__ bbias, __hip_bfloat16* __restrict__ pairz)
{
  __shared__ __align__(16) float Wl[4][128][12];  // col c = g*11+j (j<11), padded
  __shared__ __align__(16) float gl[128], bl[128];
  __shared__ float stats[512][2];
  const int tid = threadIdx.x;
  const int w = tid >> 6, l = tid & 63;
  const size_t pairbase = (size_t)blockIdx.x * 512;
  const float4* zf4 = (const float4*)z;  // 32 float4 per pair row

  for (int e = tid; e < 4 * 128 * 12; e += 256) {
    int g = e / (128 * 12); int rm = e % (128 * 12); int r = rm / 12; int j = rm % 12;
    int c = g * 11 + j;
    float v = 0.f;
    if (j < 11) v = (c < 12) ? Wb[r * 12 + c] : Wdz[r * 32 + (c - 12)];
    Wl[g][r][j] = v;
  }
  if (tid < 128) { gl[tid] = g_z[tid]; bl[tid] = b_z[tid]; }

  // stats: wave processes 4 rows at a time, 16 lanes cooperate per row
  for (int it = 0; it < 32; it++) {
    int plocal = w * 128 + it * 4 + (l >> 4);
    size_t rb = (pairbase + plocal) * 32;
    float4 a4 = zf4[rb + (l & 15)];
    float4 b4 = zf4[rb + (l & 15) + 16];
    float s1 = a4.x + a4.y + a4.z + a4.w + b4.x + b4.y + b4.z + b4.w;
    float s2 = a4.x*a4.x + a4.y*a4.y + a4.z*a4.z + a4.w*a4.w
             + b4.x*b4.x + b4.y*b4.y + b4.z*b4.z + b4.w*b4.w;
    #pragma unroll
    for (int m = 1; m < 16; m <<= 1) { s1 += __shfl_xor(s1, m, 64); s2 += __shfl_xor(s2, m, 64); }
    if ((l & 15) == 0) {
      float mean = s1 * (1.f / 128.f);
      float var = s2 * (1.f / 128.f) - mean * mean;
      stats[plocal][0] = mean;
      stats[plocal][1] = rsqrtf(var + 1e-5f);
    }
  }
  __syncthreads();

  const int g = w;  // column group
  float accv[8][11];
  #pragma unroll
  for (int i = 0; i < 8; i++)
    #pragma unroll
    for (int c = 0; c < 11; c++) accv[i][c] = 0.f;
  float mean[8], rstd[8];
  #pragma unroll
  for (int i = 0; i < 8; i++) {
    int pl = 64 * i + l;
    mean[i] = stats[pl][0]; rstd[i] = stats[pl][1];
  }

  for (int ch = 0; ch < 16; ch++) {
    float gv[8], bv[8];
    *(float4*)&gv[0] = *(const float4*)&gl[ch * 8];
    *(float4*)&gv[4] = *(const float4*)&gl[ch * 8 + 4];
    *(float4*)&bv[0] = *(const float4*)&bl[ch * 8];
    *(float4*)&bv[4] = *(const float4*)&bl[ch * 8 + 4];
    float zn[8][8];
    #pragma unroll
    for (int i = 0; i < 8; i++) {
      int pl = 64 * i + l;
      size_t rb = (pairbase + pl) * 32;
      float4 a4 = zf4[rb + ch * 2];
      float4 b4 = zf4[rb + ch * 2 + 1];
      float f[8] = { a4.x, a4.y, a4.z, a4.w, b4.x, b4.y, b4.z, b4.w };
      #pragma unroll
      for (int j = 0; j < 8; j++) zn[i][j] = (f[j] - mean[i]) * rstd[i] * gv[j] + bv[j];
    }
    #pragma unroll
    for (int j = 0; j < 8; j++) {
      int r = ch * 8 + j;
      const float* wr = &Wl[g][r][0];
      float wv[12];
      *(float4*)&wv[0] = *(const float4*)wr;
      *(float4*)&wv[4] = *(const float4*)(wr + 4);
      *(float4*)&wv[8] = *(const float4*)(wr + 8);
      #pragma unroll
      for (int i = 0; i < 8; i++) {
        float zz = zn[i][j];
        #pragma unroll
        for (int c = 0; c < 11; c++) accv[i][c] += zz * wv[c];
      }
    }
  }
  #pragma unroll
  for (int i = 0; i < 8; i++) {
    size_t pr = pairbase + 64 * i + l;
    #pragma unroll
    for (int j = 0; j < 11; j++) {
      int c = g * 11 + j;
      if (c < 12) bbias[pr * 12 + c] = f2b(accv[i][j]);
      else        pairz[pr * 32 + (c - 12)] = f2b(accv[i][j]);
    }
  }
}

// ---------------------------------------------------------------------------
// K3: attention. One block = (b, nb, 4-query chunk). 12 heads sequential.
// ---------------------------------------------------------------------------
__global__ __launch_bounds__(256) void k_attn(
    const float* __restrict__ posq, const float* __restrict__ posk,
    const float* __restrict__ posv, const float* __restrict__ posqp,
    const float* __restrict__ poskp, const float* __restrict__ posvp,
    const float* __restrict__ posqn, const float* __restrict__ poskn,
    const __hip_bfloat16* __restrict__ bbias_, const __hip_bfloat16* __restrict__ pairz_,
    const float* __restrict__ s_mask, const int* __restrict__ key_idx,
    const float* __restrict__ trans, const float* __restrict__ rots,
    const float* __restrict__ head_w,
    float* __restrict__ feats)
{
  __shared__ float a[4][12][128];
  __shared__ float keymem[5376];
  __shared__ float qbuf[4][192];
  __shared__ float qpbuf[4][144];
  __shared__ float qnbuf[4][12];
  __shared__ float optbuf[4][288];
  __shared__ int kidx[128];
  __shared__ float kmask[128];
  __shared__ float qmask[4];
  __shared__ float rt[4][12];
  __shared__ float hwe[12];

  const int tid = threadIdx.x;
  const int bid = blockIdx.x;
  const int b = bid >> 9; const int rem = bid & 511;
  const int nb = rem >> 3; const int qc = rem & 7;
  const int rowbase = b * 2048 + nb * 32 + qc * 4;
  const size_t pairbase = ((size_t)(b * 64 + nb) * 32 + qc * 4) * 128;

  if (tid < 128) kidx[tid] = key_idx[nb * 128 + tid];
  __syncthreads();
  if (tid < 128) kmask[tid] = s_mask[b * 2048 + kidx[tid]];
  if (tid < 4) qmask[tid] = s_mask[rowbase + tid];
  if (tid < 12) hwe[tid] = -0.5f * 0.13608276348795434f * log1pf(expf(head_w[tid]));
  for (int e = tid; e < 4 * 192; e += 256) { int i = e / 192, c = e % 192; qbuf[i][c] = posq[(size_t)(rowbase + i) * 192 + c]; }
  for (int e = tid; e < 4 * 144; e += 256) { int i = e / 144, c = e % 144; qpbuf[i][c] = posqp[(size_t)(rowbase + i) * 144 + c]; }
  for (int e = tid; e < 48; e += 256) { int i = e / 12, c = e % 12; qnbuf[i][c] = posqn[(size_t)(rowbase + i) * 12 + c]; }
  for (int e = tid; e < 48; e += 256) {
    int i = e / 12, c = e % 12;
    rt[i][c] = (c < 9) ? rots[(size_t)(rowbase + i) * 9 + c]
                       : trans[(size_t)(rowbase + i) * 3 + (c - 9)];
  }
  __syncthreads();

  // logits init: sqrt(1/3)*bbias + mask
  for (int e = tid; e < 4 * 128 * 12; e += 256) {
    int q = e / 1536; int rm2 = e % 1536; int k = rm2 / 12; int h = rm2 % 12;
    float bb = b2f(bbias_[(pairbase + q * 128 + k) * 12 + h]);
    a[q][h][k] = 0.5773502691896258f * bb + 100000.0f * (qmask[q] * kmask[k] - 1.0f);
  }
  __syncthreads();

  float* kbuf  = keymem;         // [128][17]
  float* kpbuf = keymem + 2176;  // [128][13]
  float* knb   = keymem + 3840;  // [128]
  float* vbuf  = keymem;         // [128][17]
  float* vpbuf = keymem + 2176;  // [128][25]
  float* pzbuf = keymem;         // [128][32]

  for (int h = 0; h < 12; h++) {
    for (int e = tid; e < 2048; e += 256) { int j = e >> 4, c = e & 15; kbuf[j * 17 + c] = posk[(size_t)(b * 2048 + kidx[j]) * 192 + h * 16 + c]; }
    for (int e = tid; e < 1536; e += 256) { int j = e / 12, u = e % 12; kpbuf[j * 13 + u] = poskp[(size_t)(b * 2048 + kidx[j]) * 144 + h * 12 + u]; }
    for (int e = tid; e < 128; e += 256) { knb[e] = poskn[(size_t)(b * 2048 + kidx[e]) * 12 + h]; }
    __syncthreads();

    for (int t2 = tid; t2 < 512; t2 += 256) {
      int q = t2 >> 7, k = t2 & 127;
      float s1 = 0.f;
      #pragma unroll
      for (int c = 0; c < 16; c++) s1 += qbuf[q][h * 16 + c] * kbuf[k * 17 + c];
      float s2 = 0.f;
      #pragma unroll
      for (int u = 0; u < 12; u++) s2 += qpbuf[q][h * 12 + u] * kpbuf[k * 13 + u];
      float pt = qnbuf[q][h] + knb[k] - 2.f * s2;
      a[q][h][k] += 0.14433756729740643f * s1 + hwe[h] * pt;
    }
    __syncthreads();

    {
      int w = tid >> 6, l = tid & 63;
      float x0 = a[w][h][l], x1 = a[w][h][l + 64];
      float mx = fmaxf(x0, x1);
      #pragma unroll
      for (int m = 1; m < 64; m <<= 1) mx = fmaxf(mx, __shfl_xor(mx, m, 64));
      float e0 = __expf(x0 - mx), e1 = __expf(x1 - mx);
      float sm = e0 + e1;
      #pragma unroll
      for (int m = 1; m < 64; m <<= 1) sm += __shfl_xor(sm, m, 64);
      float inv = 1.f / sm;
      a[w][h][l] = e0 * inv; a[w][h][l + 64] = e1 * inv;
    }
    __syncthreads();

    for (int e = tid; e < 2048; e += 256) { int j = e >> 4, c = e & 15; vbuf[j * 17 + c] = posv[(size_t)(b * 2048 + kidx[j]) * 192 + h * 16 + c]; }
    for (int e = tid; e < 3072; e += 256) { int j = e / 24, u = e % 24; vpbuf[j * 25 + u] = posvp[(size_t)(b * 2048 + kidx[j]) * 288 + h * 24 + u]; }
    __syncthreads();

    if (tid < 64) {
      int q = tid >> 4, c = tid & 15;
      float accv = 0.f;
      for (int k = 0; k < 128; k++) accv += a[q][h][k] * vbuf[k * 17 + c];
      feats[(size_t)(rowbase + q) * 960 + h * 16 + c] = accv;
    } else if (tid < 160) {
      int t2 = tid - 64; int q = t2 / 24, u = t2 % 24;
      float accv = 0.f;
      for (int k = 0; k < 128; k++) accv += a[q][h][k] * vpbuf[k * 25 + u];
      optbuf[q][h * 24 + u] = accv;
    }
    __syncthreads();
  }

  // o_pair
  for (int q = 0; q < 4; q++) {
    for (int e = tid; e < 4096; e += 256) pzbuf[e] = b2f(pairz_[(pairbase + q * 128) * 32 + e]);
    __syncthreads();
    for (int t2 = tid; t2 < 384; t2 += 256) {
      int h = t2 >> 5, c = t2 & 31;
      float accv = 0.f;
      for (int k = 0; k < 128; k++) accv += a[q][h][k] * pzbuf[k * 32 + c];
      feats[(size_t)(rowbase + q) * 960 + 576 + h * 32 + c] = accv;
    }
    __syncthreads();
  }

  // o_pt: inverse rotation + norms
  for (int t2 = tid; t2 < 384; t2 += 256) {
    int q = t2 / 96; int rm2 = t2 % 96; int h = rm2 >> 3; int v = rm2 & 7;
    float u0 = optbuf[q][h * 24 + v * 3 + 0] - rt[q][9];
    float u1 = optbuf[q][h * 24 + v * 3 + 1] - rt[q][10];
    float u2 = optbuf[q][h * 24 + v * 3 + 2] - rt[q][11];
    float w0 = rt[q][0] * u0 + rt[q][3] * u1 + rt[q][6] * u2;
    float w1 = rt[q][1] * u0 + rt[q][4] * u1 + rt[q][7] * u2;
    float w2 = rt[q][2] * u0 + rt[q][5] * u1 + rt[q][8] * u2;
    size_t fb = (size_t)(rowbase + q) * 960;
    feats[fb + 192 + h * 24 + v * 3 + 0] = w0;
    feats[fb + 192 + h * 24 + v * 3 + 1] = w1;
    feats[fb + 192 + h * 24 + v * 3 + 2] = w2;
    feats[fb + 480 + h * 8 + v] = sqrtf(w0 * w0 + w1 * w1 + w2 * w2 + 1e-8f);
  }
}

// ---------------------------------------------------------------------------
// K4: out = feats(4096x960) @ Wout(960x384) -> f32. 16 rows per block.
// ---------------------------------------------------------------------------
__global__ __launch_bounds__(256) void k_out(
    const float* __restrict__ feats, const float* __restrict__ Wout,
    float* __restrict__ out)
{
  __shared__ __align__(16) float frow[16][960];
  const int tid = threadIdx.x;
  const int p0 = blockIdx.x * 16;
  for (int e = tid; e < 16 * 240; e += 256) {
    int i = e / 240, cc = e % 240;
    ((float4*)&frow[i][0])[cc] = ((const float4*)&feats[(size_t)(p0 + i) * 960])[cc];
  }
  __syncthreads();
  const int w = tid >> 6, l = tid & 63;
  const int c0 = l * 6;
  float acc[4][6];
  #pragma unroll
  for (int i = 0; i < 4; i++)
    #pragma unroll
    for (int j = 0; j < 6; j++) acc[i][j] = 0.f;

  for (int ch = 0; ch < 240; ch++) {
    float4 f4[4];
    #pragma unroll
    for (int i = 0; i < 4; i++) f4[i] = *(const float4*)&frow[w * 4 + i][ch * 4];
    #pragma unroll
    for (int rr = 0; rr < 4; rr++) {
      int r = ch * 4 + rr;
      const float2* wp = (const float2*)(Wout + (size_t)r * 384 + c0);
      float2 w0 = wp[0], w1 = wp[1], w2 = wp[2];
      float wv[6] = { w0.x, w0.y, w1.x, w1.y, w2.x, w2.y };
      #pragma unroll
      for (int i = 0; i < 4; i++) {
        float fv = ((const float*)&f4[i])[rr];
        #pragma unroll
        for (int j = 0; j < 6; j++) acc[i][j] += fv * wv[j];
      }
    }
  }
  #pragma unroll
  for (int i = 0; i < 4; i++)
    #pragma unroll
    for (int j = 0; j < 6; j++)
      out[(size_t)(p0 + w * 4 + i) * 384 + c0 + j] = acc[i][j];
}

// ---------------------------------------------------------------------------
extern "C" void kernel_launch(void* const* d_in, const int* in_sizes, int n_in,
                              void* d_out, int out_size, void* d_ws, size_t ws_size,
                              hipStream_t stream) {
  const float* s      = (const float*)d_in[0];
  const float* z      = (const float*)d_in[1];
  const float* trans  = (const float*)d_in[2];
  const float* rots   = (const float*)d_in[3];
  const float* s_mask = (const float*)d_in[4];
  const int*   key_idx= (const int*)d_in[5];
  const float* ln_s_g = (const float*)d_in[6];
  const float* ln_s_b = (const float*)d_in[7];
  const float* ln_z_g = (const float*)d_in[8];
  const float* ln_z_b = (const float*)d_in[9];
  const float* Wq     = (const float*)d_in[10];
  const float* Wk     = (const float*)d_in[11];
  const float* Wv     = (const float*)d_in[12];
  const float* Wqp    = (const float*)d_in[13];
  const float* Wkvp   = (const float*)d_in[14];
  const float* Wb     = (const float*)d_in[15];
  const float* Wdz    = (const float*)d_in[16];
  const float* head_w = (const float*)d_in[17];
  const float* Wout   = (const float*)d_in[18];

  char* wsb = (char*)d_ws;
  // f32 workspace layout (bytes)
  float* posq  = (float*)(wsb + 0);          // 2*2048*192
  float* posk  = (float*)(wsb + 3145728);
  float* posv  = (float*)(wsb + 6291456);
  float* posqp = (float*)(wsb + 9437184);    // 2*2048*144
  float* poskp = (float*)(wsb + 11796480);
  float* posvp = (float*)(wsb + 14155776);   // 2*2048*288
  float* posqn = (float*)(wsb + 18874368);   // 2*2048*12
  float* poskn = (float*)(wsb + 19070976);
  float* feats = (float*)(wsb + 19267584);   // 4096*960
  __hip_bfloat16* bbias = (__hip_bfloat16*)(wsb + 34996224);  // 524288*12 bf16
  __hip_bfloat16* pairz = (__hip_bfloat16*)(wsb + 47579136);  // 524288*32 bf16
  // total: 81,133,568 bytes

  k_proj<<<512, 256, 0, stream>>>(s, trans, rots, ln_s_g, ln_s_b,
                                  Wq, Wk, Wv, Wqp, Wkvp,
                                  posq, posk, posv, posqp, poskp, posvp, posqn, poskn);
  k_z<<<1024, 256, 0, stream>>>(z, ln_z_g, ln_z_b, Wb, Wdz, bbias, pairz);
  k_attn<<<1024, 256, 0, stream>>>(posq, posk, posv, posqp, poskp, posvp, posqn, poskn,
                                   bbias, pairz, s_mask, key_idx, trans, rots, head_w,
                                   feats);
  k_out<<<256, 256, 0, stream>>>(feats, Wout, (float*)d_out);
}

// Round 3
// 1293.004 us; speedup vs baseline: 1.4151x; 1.4151x over previous
//
#include <hip/hip_runtime.h>
#include <hip/hip_bf16.h>

// Problem constants (BlockInvariantPointAttention):
// B=2 N=2048 BQ=32 BK=128 NB=64 CS=384 CZ=128 CH=16 H=12 PQK=4 PV=8
// feats per row: o(192) | o_pt_f(288) | o_pt_d(96) | o_pair(384) = 960
// All float inputs/outputs are FLOAT32; key_idx int32.
// s-path: k_ln -> k_pgemm (tiled GEMM 4096x1152x384) -> k_rot (scatter).

__device__ __forceinline__ float b2f(const __hip_bfloat16 x) { return __bfloat162float(x); }
__device__ __forceinline__ __hip_bfloat16 f2b(float x) { return __float2bfloat16(x); }

// ---------------------------------------------------------------------------
// K0: LayerNorm of s -> sN.  8 rows/block, one wave per 2 rows, no LDS.
// ---------------------------------------------------------------------------
__global__ __launch_bounds__(256) void k_ln(
    const float* __restrict__ s, const float* __restrict__ g_s,
    const float* __restrict__ b_s, float* __restrict__ sN)
{
  const int tid = threadIdx.x;
  const int w = tid >> 6, l = tid & 63;
  #pragma unroll
  for (int ii = 0; ii < 2; ii++) {
    int row = blockIdx.x * 8 + w * 2 + ii;
    const float* sr = s + (size_t)row * 384;
    float x[6], s1 = 0.f, s2 = 0.f;
    #pragma unroll
    for (int j = 0; j < 6; j++) { x[j] = sr[l + j * 64]; s1 += x[j]; s2 += x[j] * x[j]; }
    #pragma unroll
    for (int m = 1; m < 64; m <<= 1) { s1 += __shfl_xor(s1, m, 64); s2 += __shfl_xor(s2, m, 64); }
    float mean = s1 * (1.f / 384.f);
    float var = s2 * (1.f / 384.f) - mean * mean;
    float rstd = rsqrtf(var + 1e-5f);
    float* dr = sN + (size_t)row * 384;
    #pragma unroll
    for (int j = 0; j < 6; j++) {
      int c = l + j * 64;
      dr[c] = (x[j] - mean) * rstd * g_s[c] + b_s[c];
    }
  }
}

// ---------------------------------------------------------------------------
// K1: proj = sN(4096x384) @ Wcat(384x1152).  BM=32 BN=128 BK=16.
// grid = 64 mtiles (fast) x 9 ntiles = 1152 blocks, 256 threads.
// Each thread: 4m x 4n accumulator.
// ---------------------------------------------------------------------------
__global__ __launch_bounds__(256) void k_pgemm(
    const float* __restrict__ sN,
    const float* __restrict__ Wq, const float* __restrict__ Wk,
    const float* __restrict__ Wv, const float* __restrict__ Wqp,
    const float* __restrict__ Wkvp,
    float* __restrict__ proj)
{
  __shared__ __align__(16) float sA[16][32];    // [k][m]
  __shared__ __align__(16) float sB[16][128];   // [k][n]
  const int tid = threadIdx.x;
  const int mt = blockIdx.x & 127;              // 0..127
  const int nt = blockIdx.x >> 7;               // 0..8
  const int m0 = mt * 32, n0 = nt * 128;
  const int tm = tid >> 5, tn = tid & 31;       // 8 x 32

  // Per-thread source pointers for its two sB float4 loads (column-dependent).
  // sB float4 idx: this thread loads idx = tid and tid+256; n4 = idx&31 fixed
  // per idx; col0 = n0 + 4*(idx&31).
  const float* bsrc[2]; int bstride[2]; int bk[2];
  #pragma unroll
  for (int u = 0; u < 2; u++) {
    int idx = tid + u * 256;
    int k = idx >> 5, n4 = idx & 31;
    int col0 = n0 + n4 * 4;
    const float* p; int st;
    if (col0 < 192)      { p = Wq   + col0;         st = 192; }
    else if (col0 < 384) { p = Wk   + (col0 - 192); st = 192; }
    else if (col0 < 576) { p = Wv   + (col0 - 384); st = 192; }
    else if (col0 < 720) { p = Wqp  + (col0 - 576); st = 144; }
    else                 { p = Wkvp + (col0 - 720); st = 432; }
    bsrc[u] = p; bstride[u] = st; bk[u] = k;
  }
  const int am = tid >> 2, ak4 = tid & 3;       // sA load: m, k-group (tid<128)

  float acc[4][4];
  #pragma unroll
  for (int i = 0; i < 4; i++)
    #pragma unroll
    for (int j = 0; j < 4; j++) acc[i][j] = 0.f;

  for (int k0 = 0; k0 < 384; k0 += 16) {
    // stage sB: 16x128
    #pragma unroll
    for (int u = 0; u < 2; u++) {
      float4 wv4 = *(const float4*)(bsrc[u] + (size_t)(k0 + bk[u]) * bstride[u]);
      *(float4*)&sB[bk[u]][(tid + u * 256 & 31) * 4] = wv4;
    }
    // stage sA: 32m x 16k, transposed
    if (tid < 128) {
      float4 a4 = *(const float4*)(sN + (size_t)(m0 + am) * 384 + k0 + ak4 * 4);
      sA[ak4 * 4 + 0][am] = a4.x;
      sA[ak4 * 4 + 1][am] = a4.y;
      sA[ak4 * 4 + 2][am] = a4.z;
      sA[ak4 * 4 + 3][am] = a4.w;
    }
    __syncthreads();
    #pragma unroll
    for (int kk = 0; kk < 16; kk++) {
      float4 a4 = *(const float4*)&sA[kk][tm * 4];
      float4 b4 = *(const float4*)&sB[kk][tn * 4];
      const float* av = (const float*)&a4;
      const float* bv = (const float*)&b4;
      #pragma unroll
      for (int i = 0; i < 4; i++)
        #pragma unroll
        for (int j = 0; j < 4; j++) acc[i][j] += av[i] * bv[j];
    }
    __syncthreads();
  }
  #pragma unroll
  for (int i = 0; i < 4; i++)
    *(float4*)(proj + (size_t)(m0 + tm * 4 + i) * 1152 + n0 + tn * 4) = *(float4*)&acc[i][0];
}

// ---------------------------------------------------------------------------
// K2: rotations + point norms + scatter to pos* buffers. 8 positions/block.
// ---------------------------------------------------------------------------
__global__ __launch_bounds__(256) void k_rot(
    const float* __restrict__ proj_g,
    const float* __restrict__ trans, const float* __restrict__ rots,
    float* __restrict__ posq, float* __restrict__ posk, float* __restrict__ posv,
    float* __restrict__ posqp, float* __restrict__ poskp, float* __restrict__ posvp,
    float* __restrict__ posqn, float* __restrict__ poskn)
{
  __shared__ __align__(16) float proj[8][1152];
  __shared__ float rt[8][12];
  const int tid = threadIdx.x;
  const int p0 = blockIdx.x * 8;

  for (int e = tid; e < 8 * 288; e += 256)
    ((float4*)&proj[0][0])[e] = ((const float4*)(proj_g + (size_t)p0 * 1152))[e];
  for (int e = tid; e < 8 * 12; e += 256) {
    int i = e / 12, c = e % 12;
    rt[i][c] = (c < 9) ? rots[(size_t)(p0 + i) * 9 + c]
                       : trans[(size_t)(p0 + i) * 3 + (c - 9)];
  }
  __syncthreads();

  for (int e = tid; e < 8 * 192; e += 256) {
    int i = e / 192, p = e % 192;
    float R0 = rt[i][0], R1 = rt[i][1], R2 = rt[i][2];
    float R3 = rt[i][3], R4 = rt[i][4], R5 = rt[i][5];
    float R6 = rt[i][6], R7 = rt[i][7], R8 = rt[i][8];
    float tx = rt[i][9], ty = rt[i][10], tz = rt[i][11];
    size_t pos = p0 + i;
    if (p < 48) {
      int base = 576 + p * 3;
      float v0 = proj[i][base], v1 = proj[i][base + 1], v2 = proj[i][base + 2];
      float o0 = R0 * v0 + R1 * v1 + R2 * v2 + tx;
      float o1 = R3 * v0 + R4 * v1 + R5 * v2 + ty;
      float o2 = R6 * v0 + R7 * v1 + R8 * v2 + tz;
      proj[i][base] = o0; proj[i][base + 1] = o1; proj[i][base + 2] = o2;
      posqp[pos * 144 + p * 3 + 0] = o0;
      posqp[pos * 144 + p * 3 + 1] = o1;
      posqp[pos * 144 + p * 3 + 2] = o2;
    } else {
      int p2 = p - 48;
      int base = 720 + p2 * 3;
      float v0 = proj[i][base], v1 = proj[i][base + 1], v2 = proj[i][base + 2];
      float o0 = R0 * v0 + R1 * v1 + R2 * v2 + tx;
      float o1 = R3 * v0 + R4 * v1 + R5 * v2 + ty;
      float o2 = R6 * v0 + R7 * v1 + R8 * v2 + tz;
      int h = p2 / 12, idx = p2 % 12;
      if (idx < 4) {
        proj[i][base] = o0; proj[i][base + 1] = o1; proj[i][base + 2] = o2;
        poskp[pos * 144 + h * 12 + idx * 3 + 0] = o0;
        poskp[pos * 144 + h * 12 + idx * 3 + 1] = o1;
        poskp[pos * 144 + h * 12 + idx * 3 + 2] = o2;
      } else {
        posvp[pos * 288 + h * 24 + (idx - 4) * 3 + 0] = o0;
        posvp[pos * 288 + h * 24 + (idx - 4) * 3 + 1] = o1;
        posvp[pos * 288 + h * 24 + (idx - 4) * 3 + 2] = o2;
      }
    }
  }
  __syncthreads();

  for (int e = tid; e < 96; e += 256) {
    int i = e / 12, h = e % 12;
    size_t pos = p0 + i;
    float qs = 0.f, ks = 0.f;
    #pragma unroll
    for (int u = 0; u < 12; u++) {
      float a_ = proj[i][576 + h * 12 + u];
      qs += a_ * a_;
      float c_ = proj[i][720 + h * 36 + u];
      ks += c_ * c_;
    }
    posqn[pos * 12 + h] = qs;
    poskn[pos * 12 + h] = ks;
  }
  for (int e = tid; e < 8 * 576; e += 256) {
    int i = e / 576, c = e % 576;
    size_t pos = p0 + i;
    float v = proj[i][c];
    if (c < 192)      posq[pos * 192 + c]         = v;
    else if (c < 384) posk[pos * 192 + (c - 192)] = v;
    else              posv[pos * 192 + (c - 384)] = v;
  }
}

// ---------------------------------------------------------------------------
// K3: z path. LN over CZ=128 then 44-col GEMV -> bbias(12) + pair_z(32), bf16.
// ---------------------------------------------------------------------------
__global__ __launch_bounds__(256) void k_z(
    const float* __restrict__ z,
    const float* __restrict__ g_z, const float* __restrict__ b_z,
    const float* __restrict__ Wb, const float* __restrict__ Wdz,
    __hip_bfloat16* __restrict__ bbias, __hip_bfloat16* __restrict__ pairz)
{
  __shared__ __align__(16) float Wl[4][128][12];
  __shared__ __align__(16) float gl[128], bl[128];
  __shared__ float stats[512][2];
  const int tid = threadIdx.x;
  const int w = tid >> 6, l = tid & 63;
  const size_t pairbase = (size_t)blockIdx.x * 512;
  const float4* zf4 = (const float4*)z;

  for (int e = tid; e < 4 * 128 * 12; e += 256) {
    int g = e / (128 * 12); int rm = e % (128 * 12); int r = rm / 12; int j = rm % 12;
    int c = g * 11 + j;
    float v = 0.f;
    if (j < 11) v = (c < 12) ? Wb[r * 12 + c] : Wdz[r * 32 + (c - 12)];
    Wl[g][r][j] = v;
  }
  if (tid < 128) { gl[tid] = g_z[tid]; bl[tid] = b_z[tid]; }

  for (int it = 0; it < 32; it++) {
    int plocal = w * 128 + it * 4 + (l >> 4);
    size_t rb = (pairbase + plocal) * 32;
    float4 a4 = zf4[rb + (l & 15)];
    float4 b4 = zf4[rb + (l & 15) + 16];
    float s1 = a4.x + a4.y + a4.z + a4.w + b4.x + b4.y + b4.z + b4.w;
    float s2 = a4.x*a4.x + a4.y*a4.y + a4.z*a4.z + a4.w*a4.w
             + b4.x*b4.x + b4.y*b4.y + b4.z*b4.z + b4.w*b4.w;
    #pragma unroll
    for (int m = 1; m < 16; m <<= 1) { s1 += __shfl_xor(s1, m, 64); s2 += __shfl_xor(s2, m, 64); }
    if ((l & 15) == 0) {
      float mean = s1 * (1.f / 128.f);
      float var = s2 * (1.f / 128.f) - mean * mean;
      stats[plocal][0] = mean;
      stats[plocal][1] = rsqrtf(var + 1e-5f);
    }
  }
  __syncthreads();

  const int g = w;
  float accv[8][11];
  #pragma unroll
  for (int i = 0; i < 8; i++)
    #pragma unroll
    for (int c = 0; c < 11; c++) accv[i][c] = 0.f;
  float mean[8], rstd[8];
  #pragma unroll
  for (int i = 0; i < 8; i++) {
    int pl = 64 * i + l;
    mean[i] = stats[pl][0]; rstd[i] = stats[pl][1];
  }

  for (int ch = 0; ch < 16; ch++) {
    float gv[8], bv[8];
    *(float4*)&gv[0] = *(const float4*)&gl[ch * 8];
    *(float4*)&gv[4] = *(const float4*)&gl[ch * 8 + 4];
    *(float4*)&bv[0] = *(const float4*)&bl[ch * 8];
    *(float4*)&bv[4] = *(const float4*)&bl[ch * 8 + 4];
    float zn[8][8];
    #pragma unroll
    for (int i = 0; i < 8; i++) {
      int pl = 64 * i + l;
      size_t rb = (pairbase + pl) * 32;
      float4 a4 = zf4[rb + ch * 2];
      float4 b4 = zf4[rb + ch * 2 + 1];
      float f[8] = { a4.x, a4.y, a4.z, a4.w, b4.x, b4.y, b4.z, b4.w };
      #pragma unroll
      for (int j = 0; j < 8; j++) zn[i][j] = (f[j] - mean[i]) * rstd[i] * gv[j] + bv[j];
    }
    #pragma unroll
    for (int j = 0; j < 8; j++) {
      int r = ch * 8 + j;
      const float* wr = &Wl[g][r][0];
      float wv[12];
      *(float4*)&wv[0] = *(const float4*)wr;
      *(float4*)&wv[4] = *(const float4*)(wr + 4);
      *(float4*)&wv[8] = *(const float4*)(wr + 8);
      #pragma unroll
      for (int i = 0; i < 8; i++) {
        float zz = zn[i][j];
        #pragma unroll
        for (int c = 0; c < 11; c++) accv[i][c] += zz * wv[c];
      }
    }
  }
  #pragma unroll
  for (int i = 0; i < 8; i++) {
    size_t pr = pairbase + 64 * i + l;
    #pragma unroll
    for (int j = 0; j < 11; j++) {
      int c = g * 11 + j;
      if (c < 12) bbias[pr * 12 + c] = f2b(accv[i][j]);
      else        pairz[pr * 32 + (c - 12)] = f2b(accv[i][j]);
    }
  }
}

// ---------------------------------------------------------------------------
// K4: attention. One block = (b, nb, 4-query chunk). 12 heads sequential.
// ---------------------------------------------------------------------------
__global__ __launch_bounds__(256) void k_attn(
    const float* __restrict__ posq, const float* __restrict__ posk,
    const float* __restrict__ posv, const float* __restrict__ posqp,
    const float* __restrict__ poskp, const float* __restrict__ posvp,
    const float* __restrict__ posqn, const float* __restrict__ poskn,
    const __hip_bfloat16* __restrict__ bbias_, const __hip_bfloat16* __restrict__ pairz_,
    const float* __restrict__ s_mask, const int* __restrict__ key_idx,
    const float* __restrict__ trans, const float* __restrict__ rots,
    const float* __restrict__ head_w,
    float* __restrict__ feats)
{
  __shared__ float a[4][12][128];
  __shared__ float keymem[5376];
  __shared__ float qbuf[4][192];
  __shared__ float qpbuf[4][144];
  __shared__ float qnbuf[4][12];
  __shared__ float optbuf[4][288];
  __shared__ int kidx[128];
  __shared__ float kmask[128];
  __shared__ float qmask[4];
  __shared__ float rt[4][12];
  __shared__ float hwe[12];

  const int tid = threadIdx.x;
  const int bid = blockIdx.x;
  const int b = bid >> 9; const int rem = bid & 511;
  const int nb = rem >> 3; const int qc = rem & 7;
  const int rowbase = b * 2048 + nb * 32 + qc * 4;
  const size_t pairbase = ((size_t)(b * 64 + nb) * 32 + qc * 4) * 128;

  if (tid < 128) kidx[tid] = key_idx[nb * 128 + tid];
  __syncthreads();
  if (tid < 128) kmask[tid] = s_mask[b * 2048 + kidx[tid]];
  if (tid < 4) qmask[tid] = s_mask[rowbase + tid];
  if (tid < 12) hwe[tid] = -0.5f * 0.13608276348795434f * log1pf(expf(head_w[tid]));
  for (int e = tid; e < 4 * 192; e += 256) { int i = e / 192, c = e % 192; qbuf[i][c] = posq[(size_t)(rowbase + i) * 192 + c]; }
  for (int e = tid; e < 4 * 144; e += 256) { int i = e / 144, c = e % 144; qpbuf[i][c] = posqp[(size_t)(rowbase + i) * 144 + c]; }
  for (int e = tid; e < 48; e += 256) { int i = e / 12, c = e % 12; qnbuf[i][c] = posqn[(size_t)(rowbase + i) * 12 + c]; }
  for (int e = tid; e < 48; e += 256) {
    int i = e / 12, c = e % 12;
    rt[i][c] = (c < 9) ? rots[(size_t)(rowbase + i) * 9 + c]
                       : trans[(size_t)(rowbase + i) * 3 + (c - 9)];
  }
  __syncthreads();

  for (int e = tid; e < 4 * 128 * 12; e += 256) {
    int q = e / 1536; int rm2 = e % 1536; int k = rm2 / 12; int h = rm2 % 12;
    float bb = b2f(bbias_[(pairbase + q * 128 + k) * 12 + h]);
    a[q][h][k] = 0.5773502691896258f * bb + 100000.0f * (qmask[q] * kmask[k] - 1.0f);
  }
  __syncthreads();

  float* kbuf  = keymem;         // [128][17]
  float* kpbuf = keymem + 2176;  // [128][13]
  float* knb   = keymem + 3840;  // [128]
  float* vbuf  = keymem;         // [128][17]
  float* vpbuf = keymem + 2176;  // [128][25]
  float* pzbuf = keymem;         // [128][32]

  for (int h = 0; h < 12; h++) {
    for (int e = tid; e < 2048; e += 256) { int j = e >> 4, c = e & 15; kbuf[j * 17 + c] = posk[(size_t)(b * 2048 + kidx[j]) * 192 + h * 16 + c]; }
    for (int e = tid; e < 1536; e += 256) { int j = e / 12, u = e % 12; kpbuf[j * 13 + u] = poskp[(size_t)(b * 2048 + kidx[j]) * 144 + h * 12 + u]; }
    for (int e = tid; e < 128; e += 256) { knb[e] = poskn[(size_t)(b * 2048 + kidx[e]) * 12 + h]; }
    __syncthreads();

    for (int t2 = tid; t2 < 512; t2 += 256) {
      int q = t2 >> 7, k = t2 & 127;
      float s1 = 0.f;
      #pragma unroll
      for (int c = 0; c < 16; c++) s1 += qbuf[q][h * 16 + c] * kbuf[k * 17 + c];
      float s2 = 0.f;
      #pragma unroll
      for (int u = 0; u < 12; u++) s2 += qpbuf[q][h * 12 + u] * kpbuf[k * 13 + u];
      float pt = qnbuf[q][h] + knb[k] - 2.f * s2;
      a[q][h][k] += 0.14433756729740643f * s1 + hwe[h] * pt;
    }
    __syncthreads();

    {
      int w = tid >> 6, l = tid & 63;
      float x0 = a[w][h][l], x1 = a[w][h][l + 64];
      float mx = fmaxf(x0, x1);
      #pragma unroll
      for (int m = 1; m < 64; m <<= 1) mx = fmaxf(mx, __shfl_xor(mx, m, 64));
      float e0 = __expf(x0 - mx), e1 = __expf(x1 - mx);
      float sm = e0 + e1;
      #pragma unroll
      for (int m = 1; m < 64; m <<= 1) sm += __shfl_xor(sm, m, 64);
      float inv = 1.f / sm;
      a[w][h][l] = e0 * inv; a[w][h][l + 64] = e1 * inv;
    }
    __syncthreads();

    for (int e = tid; e < 2048; e += 256) { int j = e >> 4, c = e & 15; vbuf[j * 17 + c] = posv[(size_t)(b * 2048 + kidx[j]) * 192 + h * 16 + c]; }
    for (int e = tid; e < 3072; e += 256) { int j = e / 24, u = e % 24; vpbuf[j * 25 + u] = posvp[(size_t)(b * 2048 + kidx[j]) * 288 + h * 24 + u]; }
    __syncthreads();

    if (tid < 64) {
      int q = tid >> 4, c = tid & 15;
      float accv = 0.f;
      for (int k = 0; k < 128; k++) accv += a[q][h][k] * vbuf[k * 17 + c];
      feats[(size_t)(rowbase + q) * 960 + h * 16 + c] = accv;
    } else if (tid < 160) {
      int t2 = tid - 64; int q = t2 / 24, u = t2 % 24;
      float accv = 0.f;
      for (int k = 0; k < 128; k++) accv += a[q][h][k] * vpbuf[k * 25 + u];
      optbuf[q][h * 24 + u] = accv;
    }
    __syncthreads();
  }

  for (int q = 0; q < 4; q++) {
    for (int e = tid; e < 4096; e += 256) pzbuf[e] = b2f(pairz_[(pairbase + q * 128) * 32 + e]);
    __syncthreads();
    for (int t2 = tid; t2 < 384; t2 += 256) {
      int h = t2 >> 5, c = t2 & 31;
      float accv = 0.f;
      for (int k = 0; k < 128; k++) accv += a[q][h][k] * pzbuf[k * 32 + c];
      feats[(size_t)(rowbase + q) * 960 + 576 + h * 32 + c] = accv;
    }
    __syncthreads();
  }

  for (int t2 = tid; t2 < 384; t2 += 256) {
    int q = t2 / 96; int rm2 = t2 % 96; int h = rm2 >> 3; int v = rm2 & 7;
    float u0 = optbuf[q][h * 24 + v * 3 + 0] - rt[q][9];
    float u1 = optbuf[q][h * 24 + v * 3 + 1] - rt[q][10];
    float u2 = optbuf[q][h * 24 + v * 3 + 2] - rt[q][11];
    float w0 = rt[q][0] * u0 + rt[q][3] * u1 + rt[q][6] * u2;
    float w1 = rt[q][1] * u0 + rt[q][4] * u1 + rt[q][7] * u2;
    float w2 = rt[q][2] * u0 + rt[q][5] * u1 + rt[q][8] * u2;
    size_t fb = (size_t)(rowbase + q) * 960;
    feats[fb + 192 + h * 24 + v * 3 + 0] = w0;
    feats[fb + 192 + h * 24 + v * 3 + 1] = w1;
    feats[fb + 192 + h * 24 + v * 3 + 2] = w2;
    feats[fb + 480 + h * 8 + v] = sqrtf(w0 * w0 + w1 * w1 + w2 * w2 + 1e-8f);
  }
}

// ---------------------------------------------------------------------------
// K5: out = feats(4096x960) @ Wout(960x384). 16 rows per block.
// ---------------------------------------------------------------------------
__global__ __launch_bounds__(256) void k_out(
    const float* __restrict__ feats, const float* __restrict__ Wout,
    float* __restrict__ out)
{
  __shared__ __align__(16) float frow[16][960];
  const int tid = threadIdx.x;
  const int p0 = blockIdx.x * 16;
  for (int e = tid; e < 16 * 240; e += 256) {
    int i = e / 240, cc = e % 240;
    ((float4*)&frow[i][0])[cc] = ((const float4*)&feats[(size_t)(p0 + i) * 960])[cc];
  }
  __syncthreads();
  const int w = tid >> 6, l = tid & 63;
  const int c0 = l * 6;
  float acc[4][6];
  #pragma unroll
  for (int i = 0; i < 4; i++)
    #pragma unroll
    for (int j = 0; j < 6; j++) acc[i][j] = 0.f;

  for (int ch = 0; ch < 240; ch++) {
    float4 f4[4];
    #pragma unroll
    for (int i = 0; i < 4; i++) f4[i] = *(const float4*)&frow[w * 4 + i][ch * 4];
    #pragma unroll
    for (int rr = 0; rr < 4; rr++) {
      int r = ch * 4 + rr;
      const float2* wp = (const float2*)(Wout + (size_t)r * 384 + c0);
      float2 w0 = wp[0], w1 = wp[1], w2 = wp[2];
      float wv[6] = { w0.x, w0.y, w1.x, w1.y, w2.x, w2.y };
      #pragma unroll
      for (int i = 0; i < 4; i++) {
        float fv = ((const float*)&f4[i])[rr];
        #pragma unroll
        for (int j = 0; j < 6; j++) acc[i][j] += fv * wv[j];
      }
    }
  }
  #pragma unroll
  for (int i = 0; i < 4; i++)
    #pragma unroll
    for (int j = 0; j < 6; j++)
      out[(size_t)(p0 + w * 4 + i) * 384 + c0 + j] = acc[i][j];
}

// ---------------------------------------------------------------------------
extern "C" void kernel_launch(void* const* d_in, const int* in_sizes, int n_in,
                              void* d_out, int out_size, void* d_ws, size_t ws_size,
                              hipStream_t stream) {
  const float* s      = (const float*)d_in[0];
  const float* z      = (const float*)d_in[1];
  const float* trans  = (const float*)d_in[2];
  const float* rots   = (const float*)d_in[3];
  const float* s_mask = (const float*)d_in[4];
  const int*   key_idx= (const int*)d_in[5];
  const float* ln_s_g = (const float*)d_in[6];
  const float* ln_s_b = (const float*)d_in[7];
  const float* ln_z_g = (const float*)d_in[8];
  const float* ln_z_b = (const float*)d_in[9];
  const float* Wq     = (const float*)d_in[10];
  const float* Wk     = (const float*)d_in[11];
  const float* Wv     = (const float*)d_in[12];
  const float* Wqp    = (const float*)d_in[13];
  const float* Wkvp   = (const float*)d_in[14];
  const float* Wb     = (const float*)d_in[15];
  const float* Wdz    = (const float*)d_in[16];
  const float* head_w = (const float*)d_in[17];
  const float* Wout   = (const float*)d_in[18];

  char* wsb = (char*)d_ws;
  float* posq  = (float*)(wsb + 0);          // 2*2048*192 f32
  float* posk  = (float*)(wsb + 3145728);
  float* posv  = (float*)(wsb + 6291456);
  float* posqp = (float*)(wsb + 9437184);    // 2*2048*144
  float* poskp = (float*)(wsb + 11796480);
  float* posvp = (float*)(wsb + 14155776);   // 2*2048*288
  float* posqn = (float*)(wsb + 18874368);   // 2*2048*12
  float* poskn = (float*)(wsb + 19070976);
  float* feats = (float*)(wsb + 19267584);   // 4096*960 f32 (15.7 MB)
  // sN shares the feats region (dead before k_attn writes feats)
  float* sN    = (float*)(wsb + 19267584);   // 4096*384 f32 (6.3 MB)
  // proj shares the bbias/pairz region (dead before k_z writes them)
  float* proj  = (float*)(wsb + 34996224);   // 4096*1152 f32 (18.9 MB)
  __hip_bfloat16* bbias = (__hip_bfloat16*)(wsb + 34996224);  // 524288*12 bf16
  __hip_bfloat16* pairz = (__hip_bfloat16*)(wsb + 47579136);  // 524288*32 bf16
  // total: 81,133,568 bytes

  k_ln<<<512, 256, 0, stream>>>(s, ln_s_g, ln_s_b, sN);
  k_pgemm<<<1152, 256, 0, stream>>>(sN, Wq, Wk, Wv, Wqp, Wkvp, proj);
  k_rot<<<512, 256, 0, stream>>>(proj, trans, rots,
                                 posq, posk, posv, posqp, poskp, posvp, posqn, poskn);
  k_z<<<1024, 256, 0, stream>>>(z, ln_z_g, ln_z_b, Wb, Wdz, bbias, pairz);
  k_attn<<<1024, 256, 0, stream>>>(posq, posk, posv, posqp, poskp, posvp, posqn, poskn,
                                   bbias, pairz, s_mask, key_idx, trans, rots, head_w,
                                   feats);
  k_out<<<256, 256, 0, stream>>>(feats, Wout, (float*)d_out);
}

// Round 4
// 1071.982 us; speedup vs baseline: 1.7068x; 1.2062x over previous
//
#include <hip/hip_runtime.h>
#include <hip/hip_bf16.h>

// Problem constants (BlockInvariantPointAttention):
// B=2 N=2048 BQ=32 BK=128 NB=64 CS=384 CZ=128 CH=16 H=12 PQK=4 PV=8
// feats per row: o(192) | o_pt_f(288) | o_pt_d(96) | o_pair(384) = 960
// All float inputs/outputs are FLOAT32; key_idx int32.
// z-path: single-pass MFMA with LN folded into GEMM epilogue:
//   zn@W = rstd*(z@W') - mean*rstd*u + v,  W'=g (.) W, u=colsum(W'), v=b@W.

__device__ __forceinline__ float b2f(const __hip_bfloat16 x) { return __bfloat162float(x); }
__device__ __forceinline__ __hip_bfloat16 f2b(float x) { return __float2bfloat16(x); }
__device__ __forceinline__ unsigned short f2bu(float x) {
  __hip_bfloat16 h = __float2bfloat16(x);
  return *(unsigned short*)&h;
}
typedef __attribute__((ext_vector_type(8))) short short8x;   // 8 bf16 (4 VGPRs)
typedef __attribute__((ext_vector_type(4))) float floatx4;   // MFMA accumulator

// ---------------------------------------------------------------------------
// K0: LayerNorm of s -> sN.  8 rows/block, one wave per 2 rows, no LDS.
// ---------------------------------------------------------------------------
__global__ __launch_bounds__(256) void k_ln(
    const float* __restrict__ s, const float* __restrict__ g_s,
    const float* __restrict__ b_s, float* __restrict__ sN)
{
  const int tid = threadIdx.x;
  const int w = tid >> 6, l = tid & 63;
  #pragma unroll
  for (int ii = 0; ii < 2; ii++) {
    int row = blockIdx.x * 8 + w * 2 + ii;
    const float* sr = s + (size_t)row * 384;
    float x[6], s1 = 0.f, s2 = 0.f;
    #pragma unroll
    for (int j = 0; j < 6; j++) { x[j] = sr[l + j * 64]; s1 += x[j]; s2 += x[j] * x[j]; }
    #pragma unroll
    for (int m = 1; m < 64; m <<= 1) { s1 += __shfl_xor(s1, m, 64); s2 += __shfl_xor(s2, m, 64); }
    float mean = s1 * (1.f / 384.f);
    float var = s2 * (1.f / 384.f) - mean * mean;
    float rstd = rsqrtf(var + 1e-5f);
    float* dr = sN + (size_t)row * 384;
    #pragma unroll
    for (int j = 0; j < 6; j++) {
      int c = l + j * 64;
      dr[c] = (x[j] - mean) * rstd * g_s[c] + b_s[c];
    }
  }
}

// ---------------------------------------------------------------------------
// K1: proj = sN(4096x384) @ Wcat(384x1152).  BM=32 BN=128 BK=16.
// ---------------------------------------------------------------------------
__global__ __launch_bounds__(256) void k_pgemm(
    const float* __restrict__ sN,
    const float* __restrict__ Wq, const float* __restrict__ Wk,
    const float* __restrict__ Wv, const float* __restrict__ Wqp,
    const float* __restrict__ Wkvp,
    float* __restrict__ proj)
{
  __shared__ __align__(16) float sA[16][32];    // [k][m]
  __shared__ __align__(16) float sB[16][128];   // [k][n]
  const int tid = threadIdx.x;
  const int mt = blockIdx.x & 127;
  const int nt = blockIdx.x >> 7;
  const int m0 = mt * 32, n0 = nt * 128;
  const int tm = tid >> 5, tn = tid & 31;

  const float* bsrc[2]; int bstride[2]; int bk[2];
  #pragma unroll
  for (int u = 0; u < 2; u++) {
    int idx = tid + u * 256;
    int k = idx >> 5, n4 = idx & 31;
    int col0 = n0 + n4 * 4;
    const float* p; int st;
    if (col0 < 192)      { p = Wq   + col0;         st = 192; }
    else if (col0 < 384) { p = Wk   + (col0 - 192); st = 192; }
    else if (col0 < 576) { p = Wv   + (col0 - 384); st = 192; }
    else if (col0 < 720) { p = Wqp  + (col0 - 576); st = 144; }
    else                 { p = Wkvp + (col0 - 720); st = 432; }
    bsrc[u] = p; bstride[u] = st; bk[u] = k;
  }
  const int am = tid >> 2, ak4 = tid & 3;

  float acc[4][4];
  #pragma unroll
  for (int i = 0; i < 4; i++)
    #pragma unroll
    for (int j = 0; j < 4; j++) acc[i][j] = 0.f;

  for (int k0 = 0; k0 < 384; k0 += 16) {
    #pragma unroll
    for (int u = 0; u < 2; u++) {
      float4 wv4 = *(const float4*)(bsrc[u] + (size_t)(k0 + bk[u]) * bstride[u]);
      *(float4*)&sB[bk[u]][(tid + u * 256 & 31) * 4] = wv4;
    }
    if (tid < 128) {
      float4 a4 = *(const float4*)(sN + (size_t)(m0 + am) * 384 + k0 + ak4 * 4);
      sA[ak4 * 4 + 0][am] = a4.x;
      sA[ak4 * 4 + 1][am] = a4.y;
      sA[ak4 * 4 + 2][am] = a4.z;
      sA[ak4 * 4 + 3][am] = a4.w;
    }
    __syncthreads();
    #pragma unroll
    for (int kk = 0; kk < 16; kk++) {
      float4 a4 = *(const float4*)&sA[kk][tm * 4];
      float4 b4 = *(const float4*)&sB[kk][tn * 4];
      const float* av = (const float*)&a4;
      const float* bv = (const float*)&b4;
      #pragma unroll
      for (int i = 0; i < 4; i++)
        #pragma unroll
        for (int j = 0; j < 4; j++) acc[i][j] += av[i] * bv[j];
    }
    __syncthreads();
  }
  #pragma unroll
  for (int i = 0; i < 4; i++)
    *(float4*)(proj + (size_t)(m0 + tm * 4 + i) * 1152 + n0 + tn * 4) = *(float4*)&acc[i][0];
}

// ---------------------------------------------------------------------------
// K2: rotations + point norms + scatter to pos* buffers. 8 positions/block.
// ---------------------------------------------------------------------------
__global__ __launch_bounds__(256) void k_rot(
    const float* __restrict__ proj_g,
    const float* __restrict__ trans, const float* __restrict__ rots,
    float* __restrict__ posq, float* __restrict__ posk, float* __restrict__ posv,
    float* __restrict__ posqp, float* __restrict__ poskp, float* __restrict__ posvp,
    float* __restrict__ posqn, float* __restrict__ poskn)
{
  __shared__ __align__(16) float proj[8][1152];
  __shared__ float rt[8][12];
  const int tid = threadIdx.x;
  const int p0 = blockIdx.x * 8;

  for (int e = tid; e < 8 * 288; e += 256)
    ((float4*)&proj[0][0])[e] = ((const float4*)(proj_g + (size_t)p0 * 1152))[e];
  for (int e = tid; e < 8 * 12; e += 256) {
    int i = e / 12, c = e % 12;
    rt[i][c] = (c < 9) ? rots[(size_t)(p0 + i) * 9 + c]
                       : trans[(size_t)(p0 + i) * 3 + (c - 9)];
  }
  __syncthreads();

  for (int e = tid; e < 8 * 192; e += 256) {
    int i = e / 192, p = e % 192;
    float R0 = rt[i][0], R1 = rt[i][1], R2 = rt[i][2];
    float R3 = rt[i][3], R4 = rt[i][4], R5 = rt[i][5];
    float R6 = rt[i][6], R7 = rt[i][7], R8 = rt[i][8];
    float tx = rt[i][9], ty = rt[i][10], tz = rt[i][11];
    size_t pos = p0 + i;
    if (p < 48) {
      int base = 576 + p * 3;
      float v0 = proj[i][base], v1 = proj[i][base + 1], v2 = proj[i][base + 2];
      float o0 = R0 * v0 + R1 * v1 + R2 * v2 + tx;
      float o1 = R3 * v0 + R4 * v1 + R5 * v2 + ty;
      float o2 = R6 * v0 + R7 * v1 + R8 * v2 + tz;
      proj[i][base] = o0; proj[i][base + 1] = o1; proj[i][base + 2] = o2;
      posqp[pos * 144 + p * 3 + 0] = o0;
      posqp[pos * 144 + p * 3 + 1] = o1;
      posqp[pos * 144 + p * 3 + 2] = o2;
    } else {
      int p2 = p - 48;
      int base = 720 + p2 * 3;
      float v0 = proj[i][base], v1 = proj[i][base + 1], v2 = proj[i][base + 2];
      float o0 = R0 * v0 + R1 * v1 + R2 * v2 + tx;
      float o1 = R3 * v0 + R4 * v1 + R5 * v2 + ty;
      float o2 = R6 * v0 + R7 * v1 + R8 * v2 + tz;
      int h = p2 / 12, idx = p2 % 12;
      if (idx < 4) {
        proj[i][base] = o0; proj[i][base + 1] = o1; proj[i][base + 2] = o2;
        poskp[pos * 144 + h * 12 + idx * 3 + 0] = o0;
        poskp[pos * 144 + h * 12 + idx * 3 + 1] = o1;
        poskp[pos * 144 + h * 12 + idx * 3 + 2] = o2;
      } else {
        posvp[pos * 288 + h * 24 + (idx - 4) * 3 + 0] = o0;
        posvp[pos * 288 + h * 24 + (idx - 4) * 3 + 1] = o1;
        posvp[pos * 288 + h * 24 + (idx - 4) * 3 + 2] = o2;
      }
    }
  }
  __syncthreads();

  for (int e = tid; e < 96; e += 256) {
    int i = e / 12, h = e % 12;
    size_t pos = p0 + i;
    float qs = 0.f, ks = 0.f;
    #pragma unroll
    for (int u = 0; u < 12; u++) {
      float a_ = proj[i][576 + h * 12 + u];
      qs += a_ * a_;
      float c_ = proj[i][720 + h * 36 + u];
      ks += c_ * c_;
    }
    posqn[pos * 12 + h] = qs;
    poskn[pos * 12 + h] = ks;
  }
  for (int e = tid; e < 8 * 576; e += 256) {
    int i = e / 576, c = e % 576;
    size_t pos = p0 + i;
    float v = proj[i][c];
    if (c < 192)      posq[pos * 192 + c]         = v;
    else if (c < 384) posk[pos * 192 + (c - 192)] = v;
    else              posv[pos * 192 + (c - 384)] = v;
  }
}

// ---------------------------------------------------------------------------
// K3: z path, single-pass MFMA. 64 pair-rows/block, 8192 blocks.
// raw = z @ W' (bf16 MFMA, f32 acc);  out = rstd*raw - mean*rstd*u + v.
// ---------------------------------------------------------------------------
__global__ __launch_bounds__(256) void k_z(
    const float* __restrict__ z,
    const float* __restrict__ g_z, const float* __restrict__ b_z,
    const float* __restrict__ Wb, const float* __restrict__ Wdz,
    __hip_bfloat16* __restrict__ bbias, __hip_bfloat16* __restrict__ pairz)
{
  __shared__ unsigned short zs[64 * 128];      // bf16 z tile, row-major
  __shared__ unsigned short Wt[48 * 128];      // bf16 W' transposed: [col][k]
  __shared__ float stats[64][2];               // mean, rstd
  __shared__ float uu[48], vv[48];
  __shared__ float bzl[128];
  const int tid = threadIdx.x;
  const int lane = tid & 63, w = tid >> 6;
  const size_t row0 = (size_t)blockIdx.x * 64;
  const float4* zf4 = (const float4*)z;

  // Stage W' = g (.) [Wb|Wdz] transposed into LDS (bf16); b_z into LDS.
  for (int e = tid; e < 48 * 128; e += 256) {
    int c = e >> 7, k = e & 127;
    float v = 0.f;
    if (c < 12)      v = g_z[k] * Wb[k * 12 + c];
    else if (c < 44) v = g_z[k] * Wdz[k * 32 + (c - 12)];
    Wt[c * 128 + k] = f2bu(v);
  }
  if (tid < 128) bzl[tid] = b_z[tid];

  // Load z tile (coalesced), stats via 32-lane shuffles, bf16 -> LDS.
  float4 zv[8];
  #pragma unroll
  for (int u = 0; u < 8; u++) {
    int e = tid + u * 256;
    int row = e >> 5, c4 = e & 31;
    zv[u] = zf4[(row0 + row) * 32 + c4];
  }
  #pragma unroll
  for (int u = 0; u < 8; u++) {
    int e = tid + u * 256;
    int row = e >> 5, c4 = e & 31;
    float4 v4 = zv[u];
    float s1 = v4.x + v4.y + v4.z + v4.w;
    float s2 = v4.x*v4.x + v4.y*v4.y + v4.z*v4.z + v4.w*v4.w;
    #pragma unroll
    for (int m = 1; m < 32; m <<= 1) { s1 += __shfl_xor(s1, m, 64); s2 += __shfl_xor(s2, m, 64); }
    if ((tid & 31) == 0) {
      float mean = s1 * (1.f / 128.f);
      float var = s2 * (1.f / 128.f) - mean * mean;
      stats[row][0] = mean;
      stats[row][1] = rsqrtf(var + 1e-5f);
    }
    unsigned int p0 = (unsigned int)f2bu(v4.x) | ((unsigned int)f2bu(v4.y) << 16);
    unsigned int p1 = (unsigned int)f2bu(v4.z) | ((unsigned int)f2bu(v4.w) << 16);
    *(uint2*)&zs[row * 128 + c4 * 4] = make_uint2(p0, p1);
  }
  __syncthreads();

  // u[c] = colsum of bf16 W' (consistent with MFMA operand); v[c] = b_z @ W.
  if (tid < 44) {
    int c = tid;
    float us = 0.f, vs = 0.f;
    for (int k = 0; k < 128; k++) {
      __hip_bfloat16 h = *(__hip_bfloat16*)&Wt[c * 128 + k];
      us += b2f(h);
      float worig = (c < 12) ? Wb[k * 12 + c] : Wdz[k * 32 + (c - 12)];
      vs += bzl[k] * worig;
    }
    uu[c] = us; vv[c] = vs;
  }

  // B fragments: bf[ntile][kchunk], lane holds B[k=quad*8+j][n=lane&15].
  const int quad = lane >> 4, r16 = lane & 15;
  short8x bf[3][4];
  #pragma unroll
  for (int nt = 0; nt < 3; nt++)
    #pragma unroll
    for (int kk = 0; kk < 4; kk++)
      bf[nt][kk] = *(const short8x*)&Wt[(nt * 16 + r16) * 128 + kk * 32 + quad * 8];

  // A fragments + MFMA: wave w handles rows w*16 .. w*16+15.
  floatx4 acc[3] = { {0,0,0,0}, {0,0,0,0}, {0,0,0,0} };
  #pragma unroll
  for (int kk = 0; kk < 4; kk++) {
    short8x af = *(const short8x*)&zs[(w * 16 + r16) * 128 + kk * 32 + quad * 8];
    #pragma unroll
    for (int nt = 0; nt < 3; nt++)
      acc[nt] = __builtin_amdgcn_mfma_f32_16x16x32_bf16(af, bf[nt][kk], acc[nt], 0, 0, 0);
  }
  __syncthreads();  // uu/vv ready

  // Epilogue: C[row][col], col = lane&15, row = quad*4 + reg.
  #pragma unroll
  for (int nt = 0; nt < 3; nt++) {
    int c = nt * 16 + r16;
    if (c < 44) {
      float uc = uu[c], vc = vv[c];
      #pragma unroll
      for (int reg = 0; reg < 4; reg++) {
        int lrow = w * 16 + quad * 4 + reg;
        float mean = stats[lrow][0], rstd = stats[lrow][1];
        float val = rstd * acc[nt][reg] - mean * rstd * uc + vc;
        size_t pr = row0 + lrow;
        if (c < 12) bbias[pr * 12 + c] = f2b(val);
        else        pairz[pr * 32 + (c - 12)] = f2b(val);
      }
    }
  }
}

// ---------------------------------------------------------------------------
// K4: attention. One block = (b, nb, 4-query chunk). 12 heads sequential.
// ---------------------------------------------------------------------------
__global__ __launch_bounds__(256) void k_attn(
    const float* __restrict__ posq, const float* __restrict__ posk,
    const float* __restrict__ posv, const float* __restrict__ posqp,
    const float* __restrict__ poskp, const float* __restrict__ posvp,
    const float* __restrict__ posqn, const float* __restrict__ poskn,
    const __hip_bfloat16* __restrict__ bbias_, const __hip_bfloat16* __restrict__ pairz_,
    const float* __restrict__ s_mask, const int* __restrict__ key_idx,
    const float* __restrict__ trans, const float* __restrict__ rots,
    const float* __restrict__ head_w,
    float* __restrict__ feats)
{
  __shared__ float a[4][12][128];
  __shared__ float keymem[5376];
  __shared__ float qbuf[4][192];
  __shared__ float qpbuf[4][144];
  __shared__ float qnbuf[4][12];
  __shared__ float optbuf[4][288];
  __shared__ int kidx[128];
  __shared__ float kmask[128];
  __shared__ float qmask[4];
  __shared__ float rt[4][12];
  __shared__ float hwe[12];

  const int tid = threadIdx.x;
  const int bid = blockIdx.x;
  const int b = bid >> 9; const int rem = bid & 511;
  const int nb = rem >> 3; const int qc = rem & 7;
  const int rowbase = b * 2048 + nb * 32 + qc * 4;
  const size_t pairbase = ((size_t)(b * 64 + nb) * 32 + qc * 4) * 128;

  if (tid < 128) kidx[tid] = key_idx[nb * 128 + tid];
  __syncthreads();
  if (tid < 128) kmask[tid] = s_mask[b * 2048 + kidx[tid]];
  if (tid < 4) qmask[tid] = s_mask[rowbase + tid];
  if (tid < 12) hwe[tid] = -0.5f * 0.13608276348795434f * log1pf(expf(head_w[tid]));
  for (int e = tid; e < 4 * 192; e += 256) { int i = e / 192, c = e % 192; qbuf[i][c] = posq[(size_t)(rowbase + i) * 192 + c]; }
  for (int e = tid; e < 4 * 144; e += 256) { int i = e / 144, c = e % 144; qpbuf[i][c] = posqp[(size_t)(rowbase + i) * 144 + c]; }
  for (int e = tid; e < 48; e += 256) { int i = e / 12, c = e % 12; qnbuf[i][c] = posqn[(size_t)(rowbase + i) * 12 + c]; }
  for (int e = tid; e < 48; e += 256) {
    int i = e / 12, c = e % 12;
    rt[i][c] = (c < 9) ? rots[(size_t)(rowbase + i) * 9 + c]
                       : trans[(size_t)(rowbase + i) * 3 + (c - 9)];
  }
  __syncthreads();

  for (int e = tid; e < 4 * 128 * 12; e += 256) {
    int q = e / 1536; int rm2 = e % 1536; int k = rm2 / 12; int h = rm2 % 12;
    float bb = b2f(bbias_[(pairbase + q * 128 + k) * 12 + h]);
    a[q][h][k] = 0.5773502691896258f * bb + 100000.0f * (qmask[q] * kmask[k] - 1.0f);
  }
  __syncthreads();

  float* kbuf  = keymem;         // [128][17]
  float* kpbuf = keymem + 2176;  // [128][13]
  float* knb   = keymem + 3840;  // [128]
  float* vbuf  = keymem;         // [128][17]
  float* vpbuf = keymem + 2176;  // [128][25]
  float* pzbuf = keymem;         // [128][32]

  for (int h = 0; h < 12; h++) {
    for (int e = tid; e < 2048; e += 256) { int j = e >> 4, c = e & 15; kbuf[j * 17 + c] = posk[(size_t)(b * 2048 + kidx[j]) * 192 + h * 16 + c]; }
    for (int e = tid; e < 1536; e += 256) { int j = e / 12, u = e % 12; kpbuf[j * 13 + u] = poskp[(size_t)(b * 2048 + kidx[j]) * 144 + h * 12 + u]; }
    for (int e = tid; e < 128; e += 256) { knb[e] = poskn[(size_t)(b * 2048 + kidx[e]) * 12 + h]; }
    __syncthreads();

    for (int t2 = tid; t2 < 512; t2 += 256) {
      int q = t2 >> 7, k = t2 & 127;
      float s1 = 0.f;
      #pragma unroll
      for (int c = 0; c < 16; c++) s1 += qbuf[q][h * 16 + c] * kbuf[k * 17 + c];
      float s2 = 0.f;
      #pragma unroll
      for (int u = 0; u < 12; u++) s2 += qpbuf[q][h * 12 + u] * kpbuf[k * 13 + u];
      float pt = qnbuf[q][h] + knb[k] - 2.f * s2;
      a[q][h][k] += 0.14433756729740643f * s1 + hwe[h] * pt;
    }
    __syncthreads();

    {
      int w = tid >> 6, l = tid & 63;
      float x0 = a[w][h][l], x1 = a[w][h][l + 64];
      float mx = fmaxf(x0, x1);
      #pragma unroll
      for (int m = 1; m < 64; m <<= 1) mx = fmaxf(mx, __shfl_xor(mx, m, 64));
      float e0 = __expf(x0 - mx), e1 = __expf(x1 - mx);
      float sm = e0 + e1;
      #pragma unroll
      for (int m = 1; m < 64; m <<= 1) sm += __shfl_xor(sm, m, 64);
      float inv = 1.f / sm;
      a[w][h][l] = e0 * inv; a[w][h][l + 64] = e1 * inv;
    }
    __syncthreads();

    for (int e = tid; e < 2048; e += 256) { int j = e >> 4, c = e & 15; vbuf[j * 17 + c] = posv[(size_t)(b * 2048 + kidx[j]) * 192 + h * 16 + c]; }
    for (int e = tid; e < 3072; e += 256) { int j = e / 24, u = e % 24; vpbuf[j * 25 + u] = posvp[(size_t)(b * 2048 + kidx[j]) * 288 + h * 24 + u]; }
    __syncthreads();

    if (tid < 64) {
      int q = tid >> 4, c = tid & 15;
      float accv = 0.f;
      for (int k = 0; k < 128; k++) accv += a[q][h][k] * vbuf[k * 17 + c];
      feats[(size_t)(rowbase + q) * 960 + h * 16 + c] = accv;
    } else if (tid < 160) {
      int t2 = tid - 64; int q = t2 / 24, u = t2 % 24;
      float accv = 0.f;
      for (int k = 0; k < 128; k++) accv += a[q][h][k] * vpbuf[k * 25 + u];
      optbuf[q][h * 24 + u] = accv;
    }
    __syncthreads();
  }

  for (int q = 0; q < 4; q++) {
    for (int e = tid; e < 4096; e += 256) pzbuf[e] = b2f(pairz_[(pairbase + q * 128) * 32 + e]);
    __syncthreads();
    for (int t2 = tid; t2 < 384; t2 += 256) {
      int h = t2 >> 5, c = t2 & 31;
      float accv = 0.f;
      for (int k = 0; k < 128; k++) accv += a[q][h][k] * pzbuf[k * 32 + c];
      feats[(size_t)(rowbase + q) * 960 + 576 + h * 32 + c] = accv;
    }
    __syncthreads();
  }

  for (int t2 = tid; t2 < 384; t2 += 256) {
    int q = t2 / 96; int rm2 = t2 % 96; int h = rm2 >> 3; int v = rm2 & 7;
    float u0 = optbuf[q][h * 24 + v * 3 + 0] - rt[q][9];
    float u1 = optbuf[q][h * 24 + v * 3 + 1] - rt[q][10];
    float u2 = optbuf[q][h * 24 + v * 3 + 2] - rt[q][11];
    float w0 = rt[q][0] * u0 + rt[q][3] * u1 + rt[q][6] * u2;
    float w1 = rt[q][1] * u0 + rt[q][4] * u1 + rt[q][7] * u2;
    float w2 = rt[q][2] * u0 + rt[q][5] * u1 + rt[q][8] * u2;
    size_t fb = (size_t)(rowbase + q) * 960;
    feats[fb + 192 + h * 24 + v * 3 + 0] = w0;
    feats[fb + 192 + h * 24 + v * 3 + 1] = w1;
    feats[fb + 192 + h * 24 + v * 3 + 2] = w2;
    feats[fb + 480 + h * 8 + v] = sqrtf(w0 * w0 + w1 * w1 + w2 * w2 + 1e-8f);
  }
}

// ---------------------------------------------------------------------------
// K5: out = feats(4096x960) @ Wout(960x384). 16 rows per block.
// ---------------------------------------------------------------------------
__global__ __launch_bounds__(256) void k_out(
    const float* __restrict__ feats, const float* __restrict__ Wout,
    float* __restrict__ out)
{
  __shared__ __align__(16) float frow[16][960];
  const int tid = threadIdx.x;
  const int p0 = blockIdx.x * 16;
  for (int e = tid; e < 16 * 240; e += 256) {
    int i = e / 240, cc = e % 240;
    ((float4*)&frow[i][0])[cc] = ((const float4*)&feats[(size_t)(p0 + i) * 960])[cc];
  }
  __syncthreads();
  const int w = tid >> 6, l = tid & 63;
  const int c0 = l * 6;
  float acc[4][6];
  #pragma unroll
  for (int i = 0; i < 4; i++)
    #pragma unroll
    for (int j = 0; j < 6; j++) acc[i][j] = 0.f;

  for (int ch = 0; ch < 240; ch++) {
    float4 f4[4];
    #pragma unroll
    for (int i = 0; i < 4; i++) f4[i] = *(const float4*)&frow[w * 4 + i][ch * 4];
    #pragma unroll
    for (int rr = 0; rr < 4; rr++) {
      int r = ch * 4 + rr;
      const float2* wp = (const float2*)(Wout + (size_t)r * 384 + c0);
      float2 w0 = wp[0], w1 = wp[1], w2 = wp[2];
      float wv[6] = { w0.x, w0.y, w1.x, w1.y, w2.x, w2.y };
      #pragma unroll
      for (int i = 0; i < 4; i++) {
        float fv = ((const float*)&f4[i])[rr];
        #pragma unroll
        for (int j = 0; j < 6; j++) acc[i][j] += fv * wv[j];
      }
    }
  }
  #pragma unroll
  for (int i = 0; i < 4; i++)
    #pragma unroll
    for (int j = 0; j < 6; j++)
      out[(size_t)(p0 + w * 4 + i) * 384 + c0 + j] = acc[i][j];
}

// ---------------------------------------------------------------------------
extern "C" void kernel_launch(void* const* d_in, const int* in_sizes, int n_in,
                              void* d_out, int out_size, void* d_ws, size_t ws_size,
                              hipStream_t stream) {
  const float* s      = (const float*)d_in[0];
  const float* z      = (const float*)d_in[1];
  const float* trans  = (const float*)d_in[2];
  const float* rots   = (const float*)d_in[3];
  const float* s_mask = (const float*)d_in[4];
  const int*   key_idx= (const int*)d_in[5];
  const float* ln_s_g = (const float*)d_in[6];
  const float* ln_s_b = (const float*)d_in[7];
  const float* ln_z_g = (const float*)d_in[8];
  const float* ln_z_b = (const float*)d_in[9];
  const float* Wq     = (const float*)d_in[10];
  const float* Wk     = (const float*)d_in[11];
  const float* Wv     = (const float*)d_in[12];
  const float* Wqp    = (const float*)d_in[13];
  const float* Wkvp   = (const float*)d_in[14];
  const float* Wb     = (const float*)d_in[15];
  const float* Wdz    = (const float*)d_in[16];
  const float* head_w = (const float*)d_in[17];
  const float* Wout   = (const float*)d_in[18];

  char* wsb = (char*)d_ws;
  float* posq  = (float*)(wsb + 0);          // 2*2048*192 f32
  float* posk  = (float*)(wsb + 3145728);
  float* posv  = (float*)(wsb + 6291456);
  float* posqp = (float*)(wsb + 9437184);    // 2*2048*144
  float* poskp = (float*)(wsb + 11796480);
  float* posvp = (float*)(wsb + 14155776);   // 2*2048*288
  float* posqn = (float*)(wsb + 18874368);   // 2*2048*12
  float* poskn = (float*)(wsb + 19070976);
  float* feats = (float*)(wsb + 19267584);   // 4096*960 f32 (15.7 MB)
  float* sN    = (float*)(wsb + 19267584);   // shares feats (dead before k_attn)
  float* proj  = (float*)(wsb + 34996224);   // shares bbias/pairz (dead before k_z)
  __hip_bfloat16* bbias = (__hip_bfloat16*)(wsb + 34996224);  // 524288*12 bf16
  __hip_bfloat16* pairz = (__hip_bfloat16*)(wsb + 47579136);  // 524288*32 bf16
  // total: 81,133,568 bytes

  k_ln<<<512, 256, 0, stream>>>(s, ln_s_g, ln_s_b, sN);
  k_pgemm<<<1152, 256, 0, stream>>>(sN, Wq, Wk, Wv, Wqp, Wkvp, proj);
  k_rot<<<512, 256, 0, stream>>>(proj, trans, rots,
                                 posq, posk, posv, posqp, poskp, posvp, posqn, poskn);
  k_z<<<8192, 256, 0, stream>>>(z, ln_z_g, ln_z_b, Wb, Wdz, bbias, pairz);
  k_attn<<<1024, 256, 0, stream>>>(posq, posk, posv, posqp, poskp, posvp, posqn, poskn,
                                   bbias, pairz, s_mask, key_idx, trans, rots, head_w,
                                   feats);
  k_out<<<256, 256, 0, stream>>>(feats, Wout, (float*)d_out);
}

// Round 5
// 768.774 us; speedup vs baseline: 2.3800x; 1.3944x over previous
//
#include <hip/hip_runtime.h>
#include <hip/hip_bf16.h>

// Problem constants (BlockInvariantPointAttention):
// B=2 N=2048 BQ=32 BK=128 NB=64 CS=384 CZ=128 CH=16 H=12 PQK=4 PV=8
// feats per row: o(192) | o_pt_f(288) | o_pt_d(96) | o_pair(384) = 960
// All float inputs/outputs are FLOAT32; key_idx int32.
// Attention path: MFMA head-pair blocks; logits contraction = [16 qk | 12 pt | 4 pad]
//   with scales folded into Kext (0.1443 on qk part, -2*hwe_h on pt part).

typedef unsigned int uint_t;
typedef unsigned short ushort_t;
__device__ __forceinline__ float b2f(const __hip_bfloat16 x) { return __bfloat162float(x); }
__device__ __forceinline__ __hip_bfloat16 f2b(float x) { return __float2bfloat16(x); }
__device__ __forceinline__ ushort_t f2bu(float x) {
  __hip_bfloat16 h = __float2bfloat16(x);
  return *(ushort_t*)&h;
}
__device__ __forceinline__ float b2fu(ushort_t u) {
  union { uint_t i; float f; } c; c.i = ((uint_t)u) << 16; return c.f;
}
__device__ __forceinline__ uint_t pack2(float a, float b) {
  return (uint_t)f2bu(a) | ((uint_t)f2bu(b) << 16);
}
typedef __attribute__((ext_vector_type(8))) short short8x;   // 8 bf16 (4 VGPRs)
typedef __attribute__((ext_vector_type(4))) float floatx4;   // MFMA accumulator

// ---------------------------------------------------------------------------
// K0: LayerNorm of s -> sN.
// ---------------------------------------------------------------------------
__global__ __launch_bounds__(256) void k_ln(
    const float* __restrict__ s, const float* __restrict__ g_s,
    const float* __restrict__ b_s, float* __restrict__ sN)
{
  const int tid = threadIdx.x;
  const int w = tid >> 6, l = tid & 63;
  #pragma unroll
  for (int ii = 0; ii < 2; ii++) {
    int row = blockIdx.x * 8 + w * 2 + ii;
    const float* sr = s + (size_t)row * 384;
    float x[6], s1 = 0.f, s2 = 0.f;
    #pragma unroll
    for (int j = 0; j < 6; j++) { x[j] = sr[l + j * 64]; s1 += x[j]; s2 += x[j] * x[j]; }
    #pragma unroll
    for (int m = 1; m < 64; m <<= 1) { s1 += __shfl_xor(s1, m, 64); s2 += __shfl_xor(s2, m, 64); }
    float mean = s1 * (1.f / 384.f);
    float var = s2 * (1.f / 384.f) - mean * mean;
    float rstd = rsqrtf(var + 1e-5f);
    float* dr = sN + (size_t)row * 384;
    #pragma unroll
    for (int j = 0; j < 6; j++) {
      int c = l + j * 64;
      dr[c] = (x[j] - mean) * rstd * g_s[c] + b_s[c];
    }
  }
}

// ---------------------------------------------------------------------------
// K1: proj = sN(4096x384) @ Wcat(384x1152).  BM=32 BN=128 BK=16.
// ---------------------------------------------------------------------------
__global__ __launch_bounds__(256) void k_pgemm(
    const float* __restrict__ sN,
    const float* __restrict__ Wq, const float* __restrict__ Wk,
    const float* __restrict__ Wv, const float* __restrict__ Wqp,
    const float* __restrict__ Wkvp,
    float* __restrict__ proj)
{
  __shared__ __align__(16) float sA[16][32];
  __shared__ __align__(16) float sB[16][128];
  const int tid = threadIdx.x;
  const int mt = blockIdx.x & 127;
  const int nt = blockIdx.x >> 7;
  const int m0 = mt * 32, n0 = nt * 128;
  const int tm = tid >> 5, tn = tid & 31;

  const float* bsrc[2]; int bstride[2]; int bk[2];
  #pragma unroll
  for (int u = 0; u < 2; u++) {
    int idx = tid + u * 256;
    int k = idx >> 5, n4 = idx & 31;
    int col0 = n0 + n4 * 4;
    const float* p; int st;
    if (col0 < 192)      { p = Wq   + col0;         st = 192; }
    else if (col0 < 384) { p = Wk   + (col0 - 192); st = 192; }
    else if (col0 < 576) { p = Wv   + (col0 - 384); st = 192; }
    else if (col0 < 720) { p = Wqp  + (col0 - 576); st = 144; }
    else                 { p = Wkvp + (col0 - 720); st = 432; }
    bsrc[u] = p; bstride[u] = st; bk[u] = k;
  }
  const int am = tid >> 2, ak4 = tid & 3;

  float acc[4][4];
  #pragma unroll
  for (int i = 0; i < 4; i++)
    #pragma unroll
    for (int j = 0; j < 4; j++) acc[i][j] = 0.f;

  for (int k0 = 0; k0 < 384; k0 += 16) {
    #pragma unroll
    for (int u = 0; u < 2; u++) {
      float4 wv4 = *(const float4*)(bsrc[u] + (size_t)(k0 + bk[u]) * bstride[u]);
      *(float4*)&sB[bk[u]][(tid + u * 256 & 31) * 4] = wv4;
    }
    if (tid < 128) {
      float4 a4 = *(const float4*)(sN + (size_t)(m0 + am) * 384 + k0 + ak4 * 4);
      sA[ak4 * 4 + 0][am] = a4.x;
      sA[ak4 * 4 + 1][am] = a4.y;
      sA[ak4 * 4 + 2][am] = a4.z;
      sA[ak4 * 4 + 3][am] = a4.w;
    }
    __syncthreads();
    #pragma unroll
    for (int kk = 0; kk < 16; kk++) {
      float4 a4 = *(const float4*)&sA[kk][tm * 4];
      float4 b4 = *(const float4*)&sB[kk][tn * 4];
      const float* av = (const float*)&a4;
      const float* bv = (const float*)&b4;
      #pragma unroll
      for (int i = 0; i < 4; i++)
        #pragma unroll
        for (int j = 0; j < 4; j++) acc[i][j] += av[i] * bv[j];
    }
    __syncthreads();
  }
  #pragma unroll
  for (int i = 0; i < 4; i++)
    *(float4*)(proj + (size_t)(m0 + tm * 4 + i) * 1152 + n0 + tn * 4) = *(float4*)&acc[i][0];
}

// ---------------------------------------------------------------------------
// K2: rotations + point norms + scatter to pos* buffers. 8 positions/block.
// ---------------------------------------------------------------------------
__global__ __launch_bounds__(256) void k_rot(
    const float* __restrict__ proj_g,
    const float* __restrict__ trans, const float* __restrict__ rots,
    float* __restrict__ posq, float* __restrict__ posk, float* __restrict__ posv,
    float* __restrict__ posqp, float* __restrict__ poskp, float* __restrict__ posvp,
    float* __restrict__ posqn, float* __restrict__ poskn)
{
  __shared__ __align__(16) float proj[8][1152];
  __shared__ float rt[8][12];
  const int tid = threadIdx.x;
  const int p0 = blockIdx.x * 8;

  for (int e = tid; e < 8 * 288; e += 256)
    ((float4*)&proj[0][0])[e] = ((const float4*)(proj_g + (size_t)p0 * 1152))[e];
  for (int e = tid; e < 8 * 12; e += 256) {
    int i = e / 12, c = e % 12;
    rt[i][c] = (c < 9) ? rots[(size_t)(p0 + i) * 9 + c]
                       : trans[(size_t)(p0 + i) * 3 + (c - 9)];
  }
  __syncthreads();

  for (int e = tid; e < 8 * 192; e += 256) {
    int i = e / 192, p = e % 192;
    float R0 = rt[i][0], R1 = rt[i][1], R2 = rt[i][2];
    float R3 = rt[i][3], R4 = rt[i][4], R5 = rt[i][5];
    float R6 = rt[i][6], R7 = rt[i][7], R8 = rt[i][8];
    float tx = rt[i][9], ty = rt[i][10], tz = rt[i][11];
    size_t pos = p0 + i;
    if (p < 48) {
      int base = 576 + p * 3;
      float v0 = proj[i][base], v1 = proj[i][base + 1], v2 = proj[i][base + 2];
      float o0 = R0 * v0 + R1 * v1 + R2 * v2 + tx;
      float o1 = R3 * v0 + R4 * v1 + R5 * v2 + ty;
      float o2 = R6 * v0 + R7 * v1 + R8 * v2 + tz;
      proj[i][base] = o0; proj[i][base + 1] = o1; proj[i][base + 2] = o2;
      posqp[pos * 144 + p * 3 + 0] = o0;
      posqp[pos * 144 + p * 3 + 1] = o1;
      posqp[pos * 144 + p * 3 + 2] = o2;
    } else {
      int p2 = p - 48;
      int base = 720 + p2 * 3;
      float v0 = proj[i][base], v1 = proj[i][base + 1], v2 = proj[i][base + 2];
      float o0 = R0 * v0 + R1 * v1 + R2 * v2 + tx;
      float o1 = R3 * v0 + R4 * v1 + R5 * v2 + ty;
      float o2 = R6 * v0 + R7 * v1 + R8 * v2 + tz;
      int h = p2 / 12, idx = p2 % 12;
      if (idx < 4) {
        proj[i][base] = o0; proj[i][base + 1] = o1; proj[i][base + 2] = o2;
        poskp[pos * 144 + h * 12 + idx * 3 + 0] = o0;
        poskp[pos * 144 + h * 12 + idx * 3 + 1] = o1;
        poskp[pos * 144 + h * 12 + idx * 3 + 2] = o2;
      } else {
        posvp[pos * 288 + h * 24 + (idx - 4) * 3 + 0] = o0;
        posvp[pos * 288 + h * 24 + (idx - 4) * 3 + 1] = o1;
        posvp[pos * 288 + h * 24 + (idx - 4) * 3 + 2] = o2;
      }
    }
  }
  __syncthreads();

  for (int e = tid; e < 96; e += 256) {
    int i = e / 12, h = e % 12;
    size_t pos = p0 + i;
    float qs = 0.f, ks = 0.f;
    #pragma unroll
    for (int u = 0; u < 12; u++) {
      float a_ = proj[i][576 + h * 12 + u];
      qs += a_ * a_;
      float c_ = proj[i][720 + h * 36 + u];
      ks += c_ * c_;
    }
    posqn[pos * 12 + h] = qs;
    poskn[pos * 12 + h] = ks;
  }
  for (int e = tid; e < 8 * 576; e += 256) {
    int i = e / 576, c = e % 576;
    size_t pos = p0 + i;
    float v = proj[i][c];
    if (c < 192)      posq[pos * 192 + c]         = v;
    else if (c < 384) posk[pos * 192 + (c - 192)] = v;
    else              posv[pos * 192 + (c - 384)] = v;
  }
}

// ---------------------------------------------------------------------------
// K3: z path, single-pass MFMA. 64 pair-rows/block, 8192 blocks.
// Outputs: bbias_t [(b*64+nb)*12+h][q*128+k] bf16 (packed 8B stores)
//          pzt    [(b*64+nb)*32+q][c(32)][k(128)] bf16 (transposed pair_z)
// ---------------------------------------------------------------------------
__global__ __launch_bounds__(256) void k_z(
    const float* __restrict__ z,
    const float* __restrict__ g_z, const float* __restrict__ b_z,
    const float* __restrict__ Wb, const float* __restrict__ Wdz,
    ushort_t* __restrict__ bbias_t, ushort_t* __restrict__ pzt)
{
  __shared__ ushort_t zs[64 * 128];
  __shared__ ushort_t Wt[48 * 128];
  __shared__ float stats[64][2];
  __shared__ float uu[48], vv[48];
  __shared__ float bzl[128];
  const int tid = threadIdx.x;
  const int lane = tid & 63, w = tid >> 6;
  const size_t row0 = (size_t)blockIdx.x * 64;
  const float4* zf4 = (const float4*)z;

  for (int e = tid; e < 48 * 128; e += 256) {
    int c = e >> 7, k = e & 127;
    float v = 0.f;
    if (c < 12)      v = g_z[k] * Wb[k * 12 + c];
    else if (c < 44) v = g_z[k] * Wdz[k * 32 + (c - 12)];
    Wt[c * 128 + k] = f2bu(v);
  }
  if (tid < 128) bzl[tid] = b_z[tid];

  float4 zv[8];
  #pragma unroll
  for (int u = 0; u < 8; u++) {
    int e = tid + u * 256;
    int row = e >> 5, c4 = e & 31;
    zv[u] = zf4[(row0 + row) * 32 + c4];
  }
  #pragma unroll
  for (int u = 0; u < 8; u++) {
    int e = tid + u * 256;
    int row = e >> 5, c4 = e & 31;
    float4 v4 = zv[u];
    float s1 = v4.x + v4.y + v4.z + v4.w;
    float s2 = v4.x*v4.x + v4.y*v4.y + v4.z*v4.z + v4.w*v4.w;
    #pragma unroll
    for (int m = 1; m < 32; m <<= 1) { s1 += __shfl_xor(s1, m, 64); s2 += __shfl_xor(s2, m, 64); }
    if ((tid & 31) == 0) {
      float mean = s1 * (1.f / 128.f);
      float var = s2 * (1.f / 128.f) - mean * mean;
      stats[row][0] = mean;
      stats[row][1] = rsqrtf(var + 1e-5f);
    }
    uint_t p0 = (uint_t)f2bu(v4.x) | ((uint_t)f2bu(v4.y) << 16);
    uint_t p1 = (uint_t)f2bu(v4.z) | ((uint_t)f2bu(v4.w) << 16);
    *(uint2*)&zs[row * 128 + c4 * 4] = make_uint2(p0, p1);
  }
  __syncthreads();

  if (tid < 44) {
    int c = tid;
    float us = 0.f, vs = 0.f;
    for (int k = 0; k < 128; k++) {
      __hip_bfloat16 h = *(__hip_bfloat16*)&Wt[c * 128 + k];
      us += b2f(h);
      float worig = (c < 12) ? Wb[k * 12 + c] : Wdz[k * 32 + (c - 12)];
      vs += bzl[k] * worig;
    }
    uu[c] = us; vv[c] = vs;
  }

  const int quad = lane >> 4, r16 = lane & 15;
  short8x bf[3][4];
  #pragma unroll
  for (int nt = 0; nt < 3; nt++)
    #pragma unroll
    for (int kk = 0; kk < 4; kk++)
      bf[nt][kk] = *(const short8x*)&Wt[(nt * 16 + r16) * 128 + kk * 32 + quad * 8];

  floatx4 acc[3] = { {0,0,0,0}, {0,0,0,0}, {0,0,0,0} };
  #pragma unroll
  for (int kk = 0; kk < 4; kk++) {
    short8x af = *(const short8x*)&zs[(w * 16 + r16) * 128 + kk * 32 + quad * 8];
    #pragma unroll
    for (int nt = 0; nt < 3; nt++)
      acc[nt] = __builtin_amdgcn_mfma_f32_16x16x32_bf16(af, bf[nt][kk], acc[nt], 0, 0, 0);
  }
  __syncthreads();  // uu/vv ready

  const int bp = (int)(blockIdx.x >> 6);           // = b*64+nb
  const int qk0 = ((int)blockIdx.x & 63) * 64;     // local (q*128+k) base
  const int qloc = qk0 >> 7;                        // q index 0..31
  const int kbase = (qk0 & 127) + w * 16 + quad * 4;
  #pragma unroll
  for (int nt = 0; nt < 3; nt++) {
    int c = nt * 16 + r16;
    if (c < 44) {
      float uc = uu[c], vc = vv[c];
      float vals[4];
      #pragma unroll
      for (int reg = 0; reg < 4; reg++) {
        int lrow = w * 16 + quad * 4 + reg;
        float mean = stats[lrow][0], rstd = stats[lrow][1];
        vals[reg] = rstd * acc[nt][reg] - mean * rstd * uc + vc;
      }
      uint2 pk = make_uint2(pack2(vals[0], vals[1]), pack2(vals[2], vals[3]));
      if (c < 12) {
        size_t el = (((size_t)(bp * 12 + c)) << 12) + qk0 + w * 16 + quad * 4;
        *(uint2*)(bbias_t + el) = pk;
      } else {
        size_t el = (((size_t)((bp * 32 + qloc) * 32 + (c - 12))) << 7) + kbase;
        *(uint2*)(pzt + el) = pk;
      }
    }
  }
}

// ---------------------------------------------------------------------------
// K4: attention. 768 blocks = (b, nb, head-pair). 4 waves = (head, q-half).
// Per wave: 8 logits MFMA -> in-register softmax -> 12 PV MFMA -> epilogues.
// ---------------------------------------------------------------------------
__global__ __launch_bounds__(256) void k_attn(
    const float* __restrict__ posq, const float* __restrict__ posk,
    const float* __restrict__ posv, const float* __restrict__ posqp,
    const float* __restrict__ poskp, const float* __restrict__ posvp,
    const float* __restrict__ posqn, const float* __restrict__ poskn,
    const ushort_t* __restrict__ bbias_t,
    const float* __restrict__ s_mask, const int* __restrict__ key_idx,
    const float* __restrict__ trans, const float* __restrict__ rots,
    const float* __restrict__ head_w,
    float* __restrict__ feats, ushort_t* __restrict__ P_ws)
{
  __shared__ __align__(16) ushort_t sK[2 * 128 * 40];  // Kext [hh][k][40] (use 0..31)
  __shared__ __align__(16) ushort_t sV[2 * 48 * 136];  // Vext [hh][c][136] (k 0..127)
  __shared__ __align__(16) ushort_t sQ[2 * 32 * 40];   // Qext [hh][q][40]
  __shared__ __align__(16) ushort_t sP[64 * 136];      // P    [w*16+row][136]
  __shared__ float sOpt[64 * 25];                      // o_pt raw [w*16+row][25]
  __shared__ float rt[32][12];
  __shared__ float kn_l[2][128];
  __shared__ float qn_l[2][32];
  __shared__ float kmask[128];
  __shared__ float qmask[32];
  __shared__ int   kidx[128];
  __shared__ float hwe2[2];

  const int tid = threadIdx.x;
  const int bid = blockIdx.x;
  const int b = bid / 384;
  const int rem = bid % 384;
  const int nb = rem / 6;
  const int hp = rem % 6;
  const int h0 = hp * 2;
  const int rowbase = b * 2048 + nb * 32;

  if (tid < 128) kidx[tid] = key_idx[nb * 128 + tid];
  if (tid < 2) hwe2[tid] = -0.5f * 0.13608276348795434f * log1pf(expf(head_w[h0 + tid]));
  __syncthreads();

  if (tid < 128) kmask[tid] = s_mask[b * 2048 + kidx[tid]];
  if (tid < 32) qmask[tid] = s_mask[rowbase + tid];
  for (int e = tid; e < 384; e += 256) {
    int i = e / 12, c = e % 12;
    rt[i][c] = (c < 9) ? rots[(size_t)(rowbase + i) * 9 + c]
                       : trans[(size_t)(rowbase + i) * 3 + (c - 9)];
  }

  // ---- Kext + kn staging: thread <-> (hh, k) ----
  {
    int hh = tid >> 7, k = tid & 127, h = h0 + hh;
    int gk = b * 2048 + kidx[k];
    kn_l[hh][k] = poskn[(size_t)gk * 12 + h];
    float sq = 0.14433756729740643f;
    float sp = -2.f * hwe2[hh];
    const float* kr = posk + (size_t)gk * 192 + h * 16;
    #pragma unroll
    for (int c4 = 0; c4 < 4; c4++) {
      float4 v4 = *(const float4*)(kr + c4 * 4);
      uint2 pk = make_uint2(pack2(sq * v4.x, sq * v4.y), pack2(sq * v4.z, sq * v4.w));
      *(uint2*)&sK[(hh * 128 + k) * 40 + c4 * 4] = pk;
    }
    const float* kpr = poskp + (size_t)gk * 144 + h * 12;
    #pragma unroll
    for (int c4 = 0; c4 < 3; c4++) {
      float4 v4 = *(const float4*)(kpr + c4 * 4);
      uint2 pk = make_uint2(pack2(sp * v4.x, sp * v4.y), pack2(sp * v4.z, sp * v4.w));
      *(uint2*)&sK[(hh * 128 + k) * 40 + 16 + c4 * 4] = pk;
    }
    *(uint2*)&sK[(hh * 128 + k) * 40 + 28] = make_uint2(0u, 0u);
  }
  // ---- Vext staging (transposed, k-pairs packed): thread <-> (hh, k-pair, c-half) ----
  {
    int hh = tid >> 7, t7 = tid & 127, h = h0 + hh;
    int k2 = t7 >> 1, cg = t7 & 1, kk0 = k2 * 2;
    int ga = b * 2048 + kidx[kk0], gb = b * 2048 + kidx[kk0 + 1];
    if (cg == 0) {
      const float* A_ = posv + (size_t)ga * 192 + h * 16;
      const float* B_ = posv + (size_t)gb * 192 + h * 16;
      #pragma unroll
      for (int c4 = 0; c4 < 4; c4++) {
        float4 a4 = *(const float4*)(A_ + c4 * 4);
        float4 b4 = *(const float4*)(B_ + c4 * 4);
        #pragma unroll
        for (int j = 0; j < 4; j++)
          *(uint_t*)&sV[(hh * 48 + c4 * 4 + j) * 136 + kk0] =
              pack2(((const float*)&a4)[j], ((const float*)&b4)[j]);
      }
    } else {
      const float* A_ = posvp + (size_t)ga * 288 + h * 24;
      const float* B_ = posvp + (size_t)gb * 288 + h * 24;
      #pragma unroll
      for (int c4 = 0; c4 < 6; c4++) {
        float4 a4 = *(const float4*)(A_ + c4 * 4);
        float4 b4 = *(const float4*)(B_ + c4 * 4);
        #pragma unroll
        for (int j = 0; j < 4; j++)
          *(uint_t*)&sV[(hh * 48 + 16 + c4 * 4 + j) * 136 + kk0] =
              pack2(((const float*)&a4)[j], ((const float*)&b4)[j]);
      }
      #pragma unroll
      for (int j = 0; j < 8; j++)
        *(uint_t*)&sV[(hh * 48 + 40 + j) * 136 + kk0] = 0u;
    }
  }
  // ---- Qext + qn staging: thread <-> (hh, q), tid<64 ----
  if (tid < 64) {
    int hh = tid >> 5, q = tid & 31, h = h0 + hh;
    qn_l[hh][q] = posqn[(size_t)(rowbase + q) * 12 + h];
    const float* qr = posq + (size_t)(rowbase + q) * 192 + h * 16;
    #pragma unroll
    for (int c4 = 0; c4 < 4; c4++) {
      float4 v4 = *(const float4*)(qr + c4 * 4);
      uint2 pk = make_uint2(pack2(v4.x, v4.y), pack2(v4.z, v4.w));
      *(uint2*)&sQ[(hh * 32 + q) * 40 + c4 * 4] = pk;
    }
    const float* qpr = posqp + (size_t)(rowbase + q) * 144 + h * 12;
    #pragma unroll
    for (int c4 = 0; c4 < 3; c4++) {
      float4 v4 = *(const float4*)(qpr + c4 * 4);
      uint2 pk = make_uint2(pack2(v4.x, v4.y), pack2(v4.z, v4.w));
      *(uint2*)&sQ[(hh * 32 + q) * 40 + 16 + c4 * 4] = pk;
    }
    *(uint2*)&sQ[(hh * 32 + q) * 40 + 28] = make_uint2(0u, 0u);
  }
  __syncthreads();

  // ---- per-wave compute ----
  const int w = tid >> 6, lane = tid & 63, quad = lane >> 4, r16 = lane & 15;
  const int hh = w >> 1, q0 = (w & 1) * 16;
  const int h = h0 + hh;
  const float hwe = hwe2[hh];

  short8x af = *(const short8x*)&sQ[(hh * 32 + q0 + r16) * 40 + quad * 8];
  floatx4 acc[8];
  #pragma unroll
  for (int nt = 0; nt < 8; nt++) {
    floatx4 z4 = {0.f, 0.f, 0.f, 0.f};
    short8x bf = *(const short8x*)&sK[(hh * 128 + nt * 16 + r16) * 40 + quad * 8];
    acc[nt] = __builtin_amdgcn_mfma_f32_16x16x32_bf16(af, bf, z4, 0, 0, 0);
  }

  const ushort_t* bb = bbias_t + (((size_t)((b * 64 + nb) * 12 + h)) << 12);
  float lg[8][4];
  #pragma unroll
  for (int nt = 0; nt < 8; nt++)
    #pragma unroll
    for (int reg = 0; reg < 4; reg++) {
      int qa = q0 + quad * 4 + reg;
      lg[nt][reg] = b2fu(bb[qa * 128 + nt * 16 + r16]);
    }
  float qnv[4], qmv[4];
  #pragma unroll
  for (int reg = 0; reg < 4; reg++) {
    int qa = q0 + quad * 4 + reg;
    qnv[reg] = qn_l[hh][qa]; qmv[reg] = qmask[qa];
  }
  #pragma unroll
  for (int nt = 0; nt < 8; nt++) {
    int col = nt * 16 + r16;
    float knv = kn_l[hh][col], kmv = kmask[col];
    #pragma unroll
    for (int reg = 0; reg < 4; reg++)
      lg[nt][reg] = acc[nt][reg] + 0.5773502691896258f * lg[nt][reg]
                  + hwe * (qnv[reg] + knv) + 100000.f * (qmv[reg] * kmv - 1.f);
  }
  // softmax over 128 keys per row (in-lane over nt, xor-shuffle over r16)
  float mx[4], sm[4];
  #pragma unroll
  for (int reg = 0; reg < 4; reg++) {
    float m = lg[0][reg];
    #pragma unroll
    for (int nt = 1; nt < 8; nt++) m = fmaxf(m, lg[nt][reg]);
    #pragma unroll
    for (int d = 1; d < 16; d <<= 1) m = fmaxf(m, __shfl_xor(m, d, 64));
    mx[reg] = m; sm[reg] = 0.f;
  }
  #pragma unroll
  for (int nt = 0; nt < 8; nt++)
    #pragma unroll
    for (int reg = 0; reg < 4; reg++) {
      float e = __expf(lg[nt][reg] - mx[reg]);
      lg[nt][reg] = e; sm[reg] += e;
    }
  #pragma unroll
  for (int reg = 0; reg < 4; reg++) {
    float s = sm[reg];
    #pragma unroll
    for (int d = 1; d < 16; d <<= 1) s += __shfl_xor(s, d, 64);
    sm[reg] = 1.f / s;
  }
  // P -> LDS (wave-private)
  #pragma unroll
  for (int nt = 0; nt < 8; nt++)
    #pragma unroll
    for (int reg = 0; reg < 4; reg++) {
      int row = quad * 4 + reg;
      sP[(w * 16 + row) * 136 + nt * 16 + r16] = f2bu(lg[nt][reg] * sm[reg]);
    }
  // PV
  short8x afp[4];
  #pragma unroll
  for (int kk = 0; kk < 4; kk++)
    afp[kk] = *(const short8x*)&sP[(w * 16 + r16) * 136 + kk * 32 + quad * 8];
  floatx4 o0 = {0.f,0.f,0.f,0.f}, o1 = {0.f,0.f,0.f,0.f}, o2 = {0.f,0.f,0.f,0.f};
  #pragma unroll
  for (int kk = 0; kk < 4; kk++) {
    short8x bv0 = *(const short8x*)&sV[(hh * 48 +  0 + r16) * 136 + kk * 32 + quad * 8];
    short8x bv1 = *(const short8x*)&sV[(hh * 48 + 16 + r16) * 136 + kk * 32 + quad * 8];
    short8x bv2 = *(const short8x*)&sV[(hh * 48 + 32 + r16) * 136 + kk * 32 + quad * 8];
    o0 = __builtin_amdgcn_mfma_f32_16x16x32_bf16(afp[kk], bv0, o0, 0, 0, 0);
    o1 = __builtin_amdgcn_mfma_f32_16x16x32_bf16(afp[kk], bv1, o1, 0, 0, 0);
    o2 = __builtin_amdgcn_mfma_f32_16x16x32_bf16(afp[kk], bv2, o2, 0, 0, 0);
  }
  // o epilogue (cols 0..15 = c)
  #pragma unroll
  for (int reg = 0; reg < 4; reg++) {
    int qa = q0 + quad * 4 + reg;
    feats[(size_t)(rowbase + qa) * 960 + h * 16 + r16] = o0[reg];
  }
  // o_pt raw -> LDS
  #pragma unroll
  for (int reg = 0; reg < 4; reg++) {
    int row = quad * 4 + reg;
    sOpt[(w * 16 + row) * 25 + r16] = o1[reg];
    if (r16 < 8) sOpt[(w * 16 + row) * 25 + 16 + r16] = o2[reg];
  }
  // rotation + norm epilogue (same wave; LDS deps via waitcnt)
  for (int e2 = lane; e2 < 128; e2 += 64) {
    int ql = e2 >> 3, v = e2 & 7;
    int qa = q0 + ql;
    float u0 = sOpt[(w * 16 + ql) * 25 + v * 3 + 0] - rt[qa][9];
    float u1 = sOpt[(w * 16 + ql) * 25 + v * 3 + 1] - rt[qa][10];
    float u2 = sOpt[(w * 16 + ql) * 25 + v * 3 + 2] - rt[qa][11];
    float w0 = rt[qa][0] * u0 + rt[qa][3] * u1 + rt[qa][6] * u2;
    float w1 = rt[qa][1] * u0 + rt[qa][4] * u1 + rt[qa][7] * u2;
    float w2 = rt[qa][2] * u0 + rt[qa][5] * u1 + rt[qa][8] * u2;
    size_t fb = (size_t)(rowbase + qa) * 960;
    feats[fb + 192 + h * 24 + v * 3 + 0] = w0;
    feats[fb + 192 + h * 24 + v * 3 + 1] = w1;
    feats[fb + 192 + h * 24 + v * 3 + 2] = w2;
    feats[fb + 480 + h * 8 + v] = sqrtf(w0 * w0 + w1 * w1 + w2 * w2 + 1e-8f);
  }
  // P -> global (for k_opair), coalesced uint stores
  {
    uint_t* Pg = (uint_t*)P_ws;
    size_t pb2 = (((size_t)((b * 64 + nb) * 12 + h)) << 12) >> 1;  // uint index base
    #pragma unroll
    for (int ql = 0; ql < 16; ql++) {
      uint_t pv = *(const uint_t*)&sP[(w * 16 + ql) * 136 + 2 * lane];
      Pg[pb2 + (size_t)(q0 + ql) * 64 + lane] = pv;
    }
  }
}

// ---------------------------------------------------------------------------
// K5: o_pair. 1024 blocks = (b, nb, q-quad). wave <-> q.
// A = P [m=h(pad16)][k=key] from global; B = pzt [n=c][k=key] via LDS.
// ---------------------------------------------------------------------------
__global__ __launch_bounds__(256) void k_opair(
    const ushort_t* __restrict__ P_ws, const ushort_t* __restrict__ pzt,
    float* __restrict__ feats)
{
  __shared__ __align__(16) ushort_t pzl[4 * 32 * 136];
  const int tid = threadIdx.x;
  const int w = tid >> 6, lane = tid & 63, quad = lane >> 4, r16 = lane & 15;
  const int bid = blockIdx.x;
  const int b = bid >> 9, rem = bid & 511, nb = rem >> 3, qg = rem & 7;
  const int q = qg * 4 + w;
  const int rowbase = b * 2048 + nb * 32;

  // stage this wave's pz tile (transposed layout already): 32 c-rows x 128 k
  const uint_t* src = (const uint_t*)pzt + ((((size_t)((b * 64 + nb) * 32 + q)) << 12) >> 1);
  #pragma unroll
  for (int c = 0; c < 32; c++) {
    uint_t v = src[c * 64 + lane];
    *(uint_t*)&pzl[(w * 32 + c) * 136 + 2 * lane] = v;
  }
  // A-frags from global P
  const ushort_t* Pp = P_ws + ((size_t)(b * 64 + nb) * 12) * 4096
                            + (size_t)r16 * 4096 + (size_t)q * 128;
  short8x af[4];
  #pragma unroll
  for (int kk = 0; kk < 4; kk++)
    af[kk] = *(const short8x*)(Pp + kk * 32 + quad * 8);

  floatx4 acc[2] = { {0.f,0.f,0.f,0.f}, {0.f,0.f,0.f,0.f} };
  #pragma unroll
  for (int kk = 0; kk < 4; kk++) {
    #pragma unroll
    for (int nt = 0; nt < 2; nt++) {
      short8x bf = *(const short8x*)&pzl[(w * 32 + nt * 16 + r16) * 136 + kk * 32 + quad * 8];
      acc[nt] = __builtin_amdgcn_mfma_f32_16x16x32_bf16(af[kk], bf, acc[nt], 0, 0, 0);
    }
  }
  #pragma unroll
  for (int nt = 0; nt < 2; nt++)
    #pragma unroll
    for (int reg = 0; reg < 4; reg++) {
      int hrow = quad * 4 + reg;
      if (hrow < 12)
        feats[(size_t)(rowbase + q) * 960 + 576 + hrow * 32 + nt * 16 + r16] = acc[nt][reg];
    }
}

// ---------------------------------------------------------------------------
// K6: out = feats(4096x960) @ Wout(960x384). 16 rows per block.
// ---------------------------------------------------------------------------
__global__ __launch_bounds__(256) void k_out(
    const float* __restrict__ feats, const float* __restrict__ Wout,
    float* __restrict__ out)
{
  __shared__ __align__(16) float frow[16][960];
  const int tid = threadIdx.x;
  const int p0 = blockIdx.x * 16;
  for (int e = tid; e < 16 * 240; e += 256) {
    int i = e / 240, cc = e % 240;
    ((float4*)&frow[i][0])[cc] = ((const float4*)&feats[(size_t)(p0 + i) * 960])[cc];
  }
  __syncthreads();
  const int w = tid >> 6, l = tid & 63;
  const int c0 = l * 6;
  float acc[4][6];
  #pragma unroll
  for (int i = 0; i < 4; i++)
    #pragma unroll
    for (int j = 0; j < 6; j++) acc[i][j] = 0.f;

  for (int ch = 0; ch < 240; ch++) {
    float4 f4[4];
    #pragma unroll
    for (int i = 0; i < 4; i++) f4[i] = *(const float4*)&frow[w * 4 + i][ch * 4];
    #pragma unroll
    for (int rr = 0; rr < 4; rr++) {
      int r = ch * 4 + rr;
      const float2* wp = (const float2*)(Wout + (size_t)r * 384 + c0);
      float2 w0 = wp[0], w1 = wp[1], w2 = wp[2];
      float wv[6] = { w0.x, w0.y, w1.x, w1.y, w2.x, w2.y };
      #pragma unroll
      for (int i = 0; i < 4; i++) {
        float fv = ((const float*)&f4[i])[rr];
        #pragma unroll
        for (int j = 0; j < 6; j++) acc[i][j] += fv * wv[j];
      }
    }
  }
  #pragma unroll
  for (int i = 0; i < 4; i++)
    #pragma unroll
    for (int j = 0; j < 6; j++)
      out[(size_t)(p0 + w * 4 + i) * 384 + c0 + j] = acc[i][j];
}

// ---------------------------------------------------------------------------
extern "C" void kernel_launch(void* const* d_in, const int* in_sizes, int n_in,
                              void* d_out, int out_size, void* d_ws, size_t ws_size,
                              hipStream_t stream) {
  const float* s      = (const float*)d_in[0];
  const float* z      = (const float*)d_in[1];
  const float* trans  = (const float*)d_in[2];
  const float* rots   = (const float*)d_in[3];
  const float* s_mask = (const float*)d_in[4];
  const int*   key_idx= (const int*)d_in[5];
  const float* ln_s_g = (const float*)d_in[6];
  const float* ln_s_b = (const float*)d_in[7];
  const float* ln_z_g = (const float*)d_in[8];
  const float* ln_z_b = (const float*)d_in[9];
  const float* Wq     = (const float*)d_in[10];
  const float* Wk     = (const float*)d_in[11];
  const float* Wv     = (const float*)d_in[12];
  const float* Wqp    = (const float*)d_in[13];
  const float* Wkvp   = (const float*)d_in[14];
  const float* Wb     = (const float*)d_in[15];
  const float* Wdz    = (const float*)d_in[16];
  const float* head_w = (const float*)d_in[17];
  const float* Wout   = (const float*)d_in[18];

  char* wsb = (char*)d_ws;
  float* posq  = (float*)(wsb + 0);          // 2*2048*192 f32
  float* posk  = (float*)(wsb + 3145728);
  float* posv  = (float*)(wsb + 6291456);
  float* posqp = (float*)(wsb + 9437184);    // 2*2048*144
  float* poskp = (float*)(wsb + 11796480);
  float* posvp = (float*)(wsb + 14155776);   // 2*2048*288
  float* posqn = (float*)(wsb + 18874368);   // 2*2048*12
  float* poskn = (float*)(wsb + 19070976);
  float* feats = (float*)(wsb + 19267584);   // 4096*960 f32 (15.7 MB)
  float* sN    = (float*)(wsb + 19267584);   // shares feats (dead before k_attn)
  float* proj  = (float*)(wsb + 34996224);   // shares bbias_t region (dead before k_z)
  ushort_t* bbias_t = (ushort_t*)(wsb + 34996224);  // 12,582,912 B
  ushort_t* pzt     = (ushort_t*)(wsb + 47579136);  // 33,554,432 B
  ushort_t* P_ws    = (ushort_t*)(wsb + 81133568);  // 12,582,912 B (+32 KB slack)
  // total: 93,749,248 bytes

  k_ln<<<512, 256, 0, stream>>>(s, ln_s_g, ln_s_b, sN);
  k_pgemm<<<1152, 256, 0, stream>>>(sN, Wq, Wk, Wv, Wqp, Wkvp, proj);
  k_rot<<<512, 256, 0, stream>>>(proj, trans, rots,
                                 posq, posk, posv, posqp, poskp, posvp, posqn, poskn);
  k_z<<<8192, 256, 0, stream>>>(z, ln_z_g, ln_z_b, Wb, Wdz, bbias_t, pzt);
  k_attn<<<768, 256, 0, stream>>>(posq, posk, posv, posqp, poskp, posvp, posqn, poskn,
                                  bbias_t, s_mask, key_idx, trans, rots, head_w,
                                  feats, P_ws);
  k_opair<<<1024, 256, 0, stream>>>(P_ws, pzt, feats);
  k_out<<<256, 256, 0, stream>>>(feats, Wout, (float*)d_out);
}